// Round 1
// baseline (247.419 us; speedup 1.0000x reference)
//
#include <hip/hip_runtime.h>

typedef __attribute__((ext_vector_type(8))) short short8;
typedef __attribute__((ext_vector_type(4))) float f32x4;
typedef __attribute__((ext_vector_type(4))) unsigned short u16x4;

#define MFMA16(a, b, c) __builtin_amdgcn_mfma_f32_16x16x32_bf16(a, b, c, 0, 0, 0)

__device__ __forceinline__ unsigned short f2bf(float f) {
    union { float f; unsigned int u; } v; v.f = f;
    unsigned int r = (v.u + 0x7fffu + ((v.u >> 16) & 1u)) >> 16;
    return (unsigned short)r;
}
__device__ __forceinline__ float bf2f(unsigned short h) {
    union { unsigned int u; float f; } v; v.u = ((unsigned int)h) << 16;
    return v.f;
}

// ---------------------------------------------------------------------------
// Kernel 1: fp32 -> bf16 convert: x (2097152) then Wq,Wk,Wv,Wo (262144 each)
// ---------------------------------------------------------------------------
__global__ __launch_bounds__(256) void convertk(
    const float* __restrict__ x, const float* __restrict__ wq,
    const float* __restrict__ wk, const float* __restrict__ wv,
    const float* __restrict__ wo, unsigned short* __restrict__ xb,
    unsigned short* __restrict__ wb)
{
    int i = (blockIdx.x * 256 + threadIdx.x) * 4;   // 3072 blocks * 256 * 4 = 3145728 exact
    const float* src;
    unsigned short* dst;
    if (i < 2097152) { src = x + i; dst = xb + i; }
    else {
        int j = i - 2097152;
        int w = j >> 18;                 // 262144 = 2^18 per weight
        int o = j & 262143;
        src = (w == 0 ? wq : w == 1 ? wk : w == 2 ? wv : wo) + o;
        dst = wb + j;
    }
    float4 v = *(const float4*)src;
    u16x4 p;
    p[0] = f2bf(v.x); p[1] = f2bf(v.y); p[2] = f2bf(v.z); p[3] = f2bf(v.w);
    *(u16x4*)dst = p;
}

// ---------------------------------------------------------------------------
// Kernel 2: QKV GEMM.  C[m,n] = sum_k xb[m,k]*W[n,k] + bias[n]
// z = 0:q, 1:k  -> (B,H,L,E) bf16 ;  z = 2:v -> transposed (B,H,E,L) bf16
// Tile 128x128, BK=32, 4 waves (2x2), wave tile 64x64 = 4x4 MFMA 16x16x32.
// ---------------------------------------------------------------------------
__global__ __launch_bounds__(256) void gemm_qkv(
    const unsigned short* __restrict__ xb, const unsigned short* __restrict__ wb,
    const float* __restrict__ bq, const float* __restrict__ bk,
    const float* __restrict__ bv,
    unsigned short* __restrict__ qb, unsigned short* __restrict__ kb,
    unsigned short* __restrict__ vT)
{
    const int z = blockIdx.z;
    const unsigned short* Wz = wb + z * 262144;
    const int n0 = blockIdx.x * 128, m0 = blockIdx.y * 128;
    __shared__ unsigned short Al[128 * 40];   // stride 40 elems (80B): 16B-aligned, 2-way banks
    __shared__ unsigned short Bl[128 * 40];
    const int t = threadIdx.x;
    const int lane = t & 63, w = t >> 6;
    const int wm = (w >> 1) * 64, wn = (w & 1) * 64;
    const int quad = lane >> 4, n16 = lane & 15;
    const int rs = t >> 2, cs = (t & 3) * 8;
    f32x4 acc[4][4] = {};
    for (int k0 = 0; k0 < 512; k0 += 32) {
        __syncthreads();
        *(short8*)&Al[rs * 40 + cs]        = *(const short8*)&xb[(m0 + rs) * 512 + k0 + cs];
        *(short8*)&Al[(rs + 64) * 40 + cs] = *(const short8*)&xb[(m0 + rs + 64) * 512 + k0 + cs];
        *(short8*)&Bl[rs * 40 + cs]        = *(const short8*)&Wz[(n0 + rs) * 512 + k0 + cs];
        *(short8*)&Bl[(rs + 64) * 40 + cs] = *(const short8*)&Wz[(n0 + rs + 64) * 512 + k0 + cs];
        __syncthreads();
        short8 af[4], bf[4];
        #pragma unroll
        for (int i = 0; i < 4; i++)
            af[i] = *(const short8*)&Al[(wm + i * 16 + n16) * 40 + quad * 8];
        #pragma unroll
        for (int i = 0; i < 4; i++)
            bf[i] = *(const short8*)&Bl[(wn + i * 16 + n16) * 40 + quad * 8];
        #pragma unroll
        for (int mi = 0; mi < 4; mi++)
            #pragma unroll
            for (int ni = 0; ni < 4; ni++)
                acc[mi][ni] = MFMA16(af[mi], bf[ni], acc[mi][ni]);
    }
    const float* bias_p = (z == 0) ? bq : (z == 1) ? bk : bv;
    unsigned short* dst01 = (z == 0) ? qb : kb;
    #pragma unroll
    for (int mi = 0; mi < 4; mi++) {
        #pragma unroll
        for (int ni = 0; ni < 4; ni++) {
            const int n = n0 + wn + ni * 16 + n16;
            const int mb = m0 + wm + mi * 16 + quad * 4;
            const float bias = bias_p[n];
            const int h = n >> 6, e = n & 63;
            f32x4 v = acc[mi][ni];
            if (z < 2) {
                #pragma unroll
                for (int r = 0; r < 4; r++) {
                    int m = mb + r, b = m >> 11, l = m & 2047;
                    dst01[((b * 8 + h) * 2048 + l) * 64 + e] = f2bf(v[r] + bias);
                }
            } else {
                int b = mb >> 11, l = mb & 2047;      // 4 consecutive l, same b
                u16x4 pk;
                #pragma unroll
                for (int r = 0; r < 4; r++) pk[r] = f2bf(v[r] + bias);
                *(u16x4*)&vT[((b * 8 + h) * 64 + e) * 2048 + l] = pk;
            }
        }
    }
}

// ---------------------------------------------------------------------------
// Kernel 3: in-place interleaved RoPE on q and k (first 32 dims of each head)
// i layout: [which(1)][b*8+h(4)][l(11)][pair j(4)]  -> 2^20 threads
// ---------------------------------------------------------------------------
__global__ __launch_bounds__(256) void ropek(unsigned short* __restrict__ qb,
                                             unsigned short* __restrict__ kb)
{
    int i = blockIdx.x * 256 + threadIdx.x;
    int j = i & 15;
    int l = (i >> 4) & 2047;
    int bh = (i >> 15) & 15;
    int which = i >> 19;
    unsigned short* p = which ? kb : qb;
    int base = (bh * 2048 + l) * 64 + 2 * j;
    float t0 = bf2f(p[base]), t1 = bf2f(p[base + 1]);
    // theta_j = 10000^(-j/16)
    float theta = expf(-(float)j * 0.5756462732485115f);   // ln(10000)/16
    float ang = (float)l * theta;
    float s = sinf(ang), c = cosf(ang);
    p[base]     = f2bf(c * t0 - s * t1);
    p[base + 1] = f2bf(c * t1 + s * t0);
}

// ---------------------------------------------------------------------------
// Kernel 4: block-structured flash attention.
// grid (var=32, h=8, b=2), 256 thr = 4 independent waves of 16 Q-rows.
// vars 0..30: single causal 64x64 diagonal chunk (bias_same).
// var 31: 31 full stripe chunks (bias_diff) + causal diagonal (bias_same).
// Q/K frags direct from (B,H,L,E); V frags direct from transposed (B,H,E,L).
// P: C-layout -> per-wave LDS [s][16][40] -> A-layout b128 reads.
// ---------------------------------------------------------------------------
__global__ __launch_bounds__(256) void attn(
    const unsigned short* __restrict__ qb, const unsigned short* __restrict__ kb,
    const unsigned short* __restrict__ vT, const float* __restrict__ bias_emb,
    unsigned short* __restrict__ voutb)
{
    const int var = blockIdx.x, h = blockIdx.y, b = blockIdx.z;
    const int t = threadIdx.x, lane = t & 63, w = t >> 6;
    const int quad = lane >> 4, n16 = lane & 15;
    const int bh = b * 8 + h;
    const int m0 = var * 64 + w * 16;                 // wave's first global row (l)
    __shared__ unsigned short Pl[4 * 1280];           // per-wave [s(2)][row(16)][40]
    unsigned short* Pw = &Pl[w * 1280];
    const int qoff = bh * 2048 * 64;

    short8 aq0 = *(const short8*)&qb[qoff + (m0 + n16) * 64 + quad * 8];
    short8 aq1 = *(const short8*)&qb[qoff + (m0 + n16) * 64 + 32 + quad * 8];

    f32x4 oacc[4] = {};
    float mrow[4], lrow[4];
    #pragma unroll
    for (int r = 0; r < 4; r++) { mrow[r] = -1e30f; lrow[r] = 0.f; }
    const float scale = 0.125f;
    const float bias_same = bias_emb[8 + h];
    const float bias_diff = bias_emb[h];
    const int iloc = w * 16 + quad * 4;               // within-var row, + r

    const int nch = (var == 31) ? 32 : 1;
    for (int ci = 0; ci < nch; ci++) {
        const int chunk = (var == 31) ? ci : var;
        const bool diag = (chunk == var);
        const float biasv = diag ? bias_same : bias_diff;
        const int j0 = chunk * 64;

        // ---- S = Q K^T over this 64-col chunk
        f32x4 sc[4];
        #pragma unroll
        for (int nt = 0; nt < 4; nt++) {
            short8 k0f = *(const short8*)&kb[qoff + (j0 + nt * 16 + n16) * 64 + quad * 8];
            short8 k1f = *(const short8*)&kb[qoff + (j0 + nt * 16 + n16) * 64 + 32 + quad * 8];
            f32x4 s = {};
            s = MFMA16(aq0, k0f, s);
            s = MFMA16(aq1, k1f, s);
            sc[nt] = s;
        }
        // ---- logits + mask
        float zl[4][4];
        #pragma unroll
        for (int nt = 0; nt < 4; nt++) {
            int jloc = nt * 16 + n16;
            #pragma unroll
            for (int r = 0; r < 4; r++) {
                float zz = scale * (sc[nt][r] + biasv);
                if (diag && jloc > iloc + r) zz = -1e30f;
                zl[nt][r] = zz;
            }
        }
        // ---- row max (across 4 nt in-lane, then 16 lanes of the quad)
        float cm[4];
        #pragma unroll
        for (int r = 0; r < 4; r++)
            cm[r] = fmaxf(fmaxf(zl[0][r], zl[1][r]), fmaxf(zl[2][r], zl[3][r]));
        #pragma unroll
        for (int off = 1; off < 16; off <<= 1)
            #pragma unroll
            for (int r = 0; r < 4; r++)
                cm[r] = fmaxf(cm[r], __shfl_xor(cm[r], off));
        float mnew[4], alpha[4], rsum[4], pr[4][4];
        #pragma unroll
        for (int r = 0; r < 4; r++) {
            mnew[r] = fmaxf(mrow[r], cm[r]);
            alpha[r] = __expf(mrow[r] - mnew[r]);
        }
        #pragma unroll
        for (int nt = 0; nt < 4; nt++)
            #pragma unroll
            for (int r = 0; r < 4; r++)
                pr[nt][r] = __expf(zl[nt][r] - mnew[r]);
        #pragma unroll
        for (int r = 0; r < 4; r++)
            rsum[r] = (pr[0][r] + pr[1][r]) + (pr[2][r] + pr[3][r]);
        #pragma unroll
        for (int off = 1; off < 16; off <<= 1)
            #pragma unroll
            for (int r = 0; r < 4; r++)
                rsum[r] += __shfl_xor(rsum[r], off);
        #pragma unroll
        for (int r = 0; r < 4; r++) {
            lrow[r] = lrow[r] * alpha[r] + rsum[r];
            mrow[r] = mnew[r];
        }
        #pragma unroll
        for (int et = 0; et < 4; et++)
            #pragma unroll
            for (int r = 0; r < 4; r++)
                oacc[et][r] *= alpha[r];
        // ---- P -> LDS (C-layout scatter), layout [s][row][40]
        #pragma unroll
        for (int nt = 0; nt < 4; nt++) {
            int s = nt >> 1, c = (nt & 1) * 16 + n16;
            #pragma unroll
            for (int r = 0; r < 4; r++)
                Pw[s * 640 + (quad * 4 + r) * 40 + c] = f2bf(pr[nt][r]);
        }
        __syncthreads();
        short8 pa0 = *(const short8*)&Pw[0 * 640 + n16 * 40 + quad * 8];
        short8 pa1 = *(const short8*)&Pw[1 * 640 + n16 * 40 + quad * 8];
        // ---- O += P V  (V^T frags direct from global)
        #pragma unroll
        for (int et = 0; et < 4; et++) {
            const int vrow = (bh * 64 + et * 16 + n16) * 2048;
            short8 v0 = *(const short8*)&vT[vrow + j0 + quad * 8];
            short8 v1 = *(const short8*)&vT[vrow + j0 + 32 + quad * 8];
            oacc[et] = MFMA16(pa0, v0, oacc[et]);
            oacc[et] = MFMA16(pa1, v1, oacc[et]);
        }
        __syncthreads();   // protect Pw WAR for next chunk
    }
    // ---- normalize + store to (B,L,H*E) bf16
    #pragma unroll
    for (int et = 0; et < 4; et++) {
        #pragma unroll
        for (int r = 0; r < 4; r++) {
            float o = oacc[et][r] / lrow[r];
            int l = m0 + quad * 4 + r;
            voutb[(b * 2048 + l) * 512 + h * 64 + et * 16 + n16] = f2bf(o);
        }
    }
}

// ---------------------------------------------------------------------------
// Kernel 5: out = voutb(4096x512) @ Wo^T + bo  -> fp32 d_out
// ---------------------------------------------------------------------------
__global__ __launch_bounds__(256) void gemm_out(
    const unsigned short* __restrict__ ab, const unsigned short* __restrict__ wo,
    const float* __restrict__ bo, float* __restrict__ out)
{
    const int n0 = blockIdx.x * 128, m0 = blockIdx.y * 128;
    __shared__ unsigned short Al[128 * 40];
    __shared__ unsigned short Bl[128 * 40];
    const int t = threadIdx.x;
    const int lane = t & 63, w = t >> 6;
    const int wm = (w >> 1) * 64, wn = (w & 1) * 64;
    const int quad = lane >> 4, n16 = lane & 15;
    const int rs = t >> 2, cs = (t & 3) * 8;
    f32x4 acc[4][4] = {};
    for (int k0 = 0; k0 < 512; k0 += 32) {
        __syncthreads();
        *(short8*)&Al[rs * 40 + cs]        = *(const short8*)&ab[(m0 + rs) * 512 + k0 + cs];
        *(short8*)&Al[(rs + 64) * 40 + cs] = *(const short8*)&ab[(m0 + rs + 64) * 512 + k0 + cs];
        *(short8*)&Bl[rs * 40 + cs]        = *(const short8*)&wo[(n0 + rs) * 512 + k0 + cs];
        *(short8*)&Bl[(rs + 64) * 40 + cs] = *(const short8*)&wo[(n0 + rs + 64) * 512 + k0 + cs];
        __syncthreads();
        short8 af[4], bf[4];
        #pragma unroll
        for (int i = 0; i < 4; i++)
            af[i] = *(const short8*)&Al[(wm + i * 16 + n16) * 40 + quad * 8];
        #pragma unroll
        for (int i = 0; i < 4; i++)
            bf[i] = *(const short8*)&Bl[(wn + i * 16 + n16) * 40 + quad * 8];
        #pragma unroll
        for (int mi = 0; mi < 4; mi++)
            #pragma unroll
            for (int ni = 0; ni < 4; ni++)
                acc[mi][ni] = MFMA16(af[mi], bf[ni], acc[mi][ni]);
    }
    #pragma unroll
    for (int mi = 0; mi < 4; mi++) {
        #pragma unroll
        for (int ni = 0; ni < 4; ni++) {
            const int n = n0 + wn + ni * 16 + n16;
            const int mb = m0 + wm + mi * 16 + quad * 4;
            const float bias = bo[n];
            f32x4 v = acc[mi][ni];
            #pragma unroll
            for (int r = 0; r < 4; r++)
                out[(mb + r) * 512 + n] = v[r] + bias;
        }
    }
}

// ---------------------------------------------------------------------------
extern "C" void kernel_launch(void* const* d_in, const int* in_sizes, int n_in,
                              void* d_out, int out_size, void* d_ws, size_t ws_size,
                              hipStream_t stream)
{
    const float* x        = (const float*)d_in[0];
    const float* Wq       = (const float*)d_in[1];
    const float* bq       = (const float*)d_in[2];
    const float* Wk       = (const float*)d_in[3];
    const float* bk       = (const float*)d_in[4];
    const float* Wv       = (const float*)d_in[5];
    const float* bv       = (const float*)d_in[6];
    const float* Wo       = (const float*)d_in[7];
    const float* bo       = (const float*)d_in[8];
    const float* bias_emb = (const float*)d_in[9];

    unsigned short* xb  = (unsigned short*)d_ws;      // 2097152 elems
    unsigned short* wb  = xb + 2097152;               // 4 * 262144
    unsigned short* qb  = wb + 1048576;               // 2097152 (B,H,L,E)
    unsigned short* kb  = qb + 2097152;               // 2097152 (B,H,L,E)
    unsigned short* vT  = kb + 2097152;               // 2097152 (B,H,E,L)
    unsigned short* vob = vT + 2097152;               // 2097152 (B,L,H*E)

    hipLaunchKernelGGL(convertk, dim3(3072), dim3(256), 0, stream,
                       x, Wq, Wk, Wv, Wo, xb, wb);
    hipLaunchKernelGGL(gemm_qkv, dim3(4, 32, 3), dim3(256), 0, stream,
                       xb, wb, bq, bk, bv, qb, kb, vT);
    hipLaunchKernelGGL(ropek, dim3(4096), dim3(256), 0, stream, qb, kb);
    hipLaunchKernelGGL(attn, dim3(32, 8, 2), dim3(256), 0, stream,
                       qb, kb, vT, bias_emb, vob);
    hipLaunchKernelGGL(gemm_out, dim3(4, 32, 1), dim3(256), 0, stream,
                       vob, wb + 3 * 262144, bo, (float*)d_out);
}

// Round 2
// 140.927 us; speedup vs baseline: 1.7557x; 1.7557x over previous
//
#include <hip/hip_runtime.h>

typedef __attribute__((ext_vector_type(8))) short short8;
typedef __attribute__((ext_vector_type(4))) float f32x4;
typedef __attribute__((ext_vector_type(4))) unsigned short u16x4;

#define MFMA16(a, b, c) __builtin_amdgcn_mfma_f32_16x16x32_bf16(a, b, c, 0, 0, 0)

__device__ __forceinline__ unsigned short f2bf(float f) {
    union { float f; unsigned int u; } v; v.f = f;
    unsigned int r = (v.u + 0x7fffu + ((v.u >> 16) & 1u)) >> 16;
    return (unsigned short)r;
}
__device__ __forceinline__ float bf2f(unsigned short h) {
    union { unsigned int u; float f; } v; v.u = ((unsigned int)h) << 16;
    return v.f;
}

// ---------------------------------------------------------------------------
// Kernel 1: fp32 -> bf16 convert: x (2097152) then Wq,Wk,Wv,Wo (262144 each)
// ---------------------------------------------------------------------------
__global__ __launch_bounds__(256) void convertk(
    const float* __restrict__ x, const float* __restrict__ wq,
    const float* __restrict__ wk, const float* __restrict__ wv,
    const float* __restrict__ wo, unsigned short* __restrict__ xb,
    unsigned short* __restrict__ wb)
{
    int i = (blockIdx.x * 256 + threadIdx.x) * 4;
    const float* src;
    unsigned short* dst;
    if (i < 2097152) { src = x + i; dst = xb + i; }
    else {
        int j = i - 2097152;
        int w = j >> 18;
        int o = j & 262143;
        src = (w == 0 ? wq : w == 1 ? wk : w == 2 ? wv : wo) + o;
        dst = wb + j;
    }
    float4 v = *(const float4*)src;
    u16x4 p;
    p[0] = f2bf(v.x); p[1] = f2bf(v.y); p[2] = f2bf(v.z); p[3] = f2bf(v.w);
    *(u16x4*)dst = p;
}

// ---------------------------------------------------------------------------
// Kernel 2: QKV GEMM.  C[m,n] = sum_k xb[m,k]*W[n,k] + bias[n]
// ---------------------------------------------------------------------------
__global__ __launch_bounds__(256) void gemm_qkv(
    const unsigned short* __restrict__ xb, const unsigned short* __restrict__ wb,
    const float* __restrict__ bq, const float* __restrict__ bk,
    const float* __restrict__ bv,
    unsigned short* __restrict__ qb, unsigned short* __restrict__ kb,
    unsigned short* __restrict__ vT)
{
    const int z = blockIdx.z;
    const unsigned short* Wz = wb + z * 262144;
    const int n0 = blockIdx.x * 128, m0 = blockIdx.y * 128;
    __shared__ unsigned short Al[128 * 40];
    __shared__ unsigned short Bl[128 * 40];
    const int t = threadIdx.x;
    const int lane = t & 63, w = t >> 6;
    const int wm = (w >> 1) * 64, wn = (w & 1) * 64;
    const int quad = lane >> 4, n16 = lane & 15;
    const int rs = t >> 2, cs = (t & 3) * 8;
    f32x4 acc[4][4] = {};
    for (int k0 = 0; k0 < 512; k0 += 32) {
        __syncthreads();
        *(short8*)&Al[rs * 40 + cs]        = *(const short8*)&xb[(m0 + rs) * 512 + k0 + cs];
        *(short8*)&Al[(rs + 64) * 40 + cs] = *(const short8*)&xb[(m0 + rs + 64) * 512 + k0 + cs];
        *(short8*)&Bl[rs * 40 + cs]        = *(const short8*)&Wz[(n0 + rs) * 512 + k0 + cs];
        *(short8*)&Bl[(rs + 64) * 40 + cs] = *(const short8*)&Wz[(n0 + rs + 64) * 512 + k0 + cs];
        __syncthreads();
        short8 af[4], bf[4];
        #pragma unroll
        for (int i = 0; i < 4; i++)
            af[i] = *(const short8*)&Al[(wm + i * 16 + n16) * 40 + quad * 8];
        #pragma unroll
        for (int i = 0; i < 4; i++)
            bf[i] = *(const short8*)&Bl[(wn + i * 16 + n16) * 40 + quad * 8];
        #pragma unroll
        for (int mi = 0; mi < 4; mi++)
            #pragma unroll
            for (int ni = 0; ni < 4; ni++)
                acc[mi][ni] = MFMA16(af[mi], bf[ni], acc[mi][ni]);
    }
    const float* bias_p = (z == 0) ? bq : (z == 1) ? bk : bv;
    unsigned short* dst01 = (z == 0) ? qb : kb;
    #pragma unroll
    for (int mi = 0; mi < 4; mi++) {
        #pragma unroll
        for (int ni = 0; ni < 4; ni++) {
            const int n = n0 + wn + ni * 16 + n16;
            const int mb = m0 + wm + mi * 16 + quad * 4;
            const float bias = bias_p[n];
            const int h = n >> 6, e = n & 63;
            f32x4 v = acc[mi][ni];
            if (z < 2) {
                #pragma unroll
                for (int r = 0; r < 4; r++) {
                    int m = mb + r, b = m >> 11, l = m & 2047;
                    dst01[((b * 8 + h) * 2048 + l) * 64 + e] = f2bf(v[r] + bias);
                }
            } else {
                int b = mb >> 11, l = mb & 2047;
                u16x4 pk;
                #pragma unroll
                for (int r = 0; r < 4; r++) pk[r] = f2bf(v[r] + bias);
                *(u16x4*)&vT[((b * 8 + h) * 64 + e) * 2048 + l] = pk;
            }
        }
    }
}

// ---------------------------------------------------------------------------
// Kernel 3: in-place interleaved RoPE on q and k
// ---------------------------------------------------------------------------
__global__ __launch_bounds__(256) void ropek(unsigned short* __restrict__ qb,
                                             unsigned short* __restrict__ kb)
{
    int i = blockIdx.x * 256 + threadIdx.x;
    int j = i & 15;
    int l = (i >> 4) & 2047;
    int bh = (i >> 15) & 15;
    int which = i >> 19;
    unsigned short* p = which ? kb : qb;
    int base = (bh * 2048 + l) * 64 + 2 * j;
    float t0 = bf2f(p[base]), t1 = bf2f(p[base + 1]);
    float theta = expf(-(float)j * 0.5756462732485115f);
    float ang = (float)l * theta;
    float s = sinf(ang), c = cosf(ang);
    p[base]     = f2bf(c * t0 - s * t1);
    p[base + 1] = f2bf(c * t1 + s * t0);
}

// ---------------------------------------------------------------------------
// Kernel 4a: diagonal blocks, vars 0..30. One-pass softmax, no barriers
// (P LDS region is per-wave private; within-wave lgkmcnt handles ordering).
// ---------------------------------------------------------------------------
__global__ __launch_bounds__(256) void attn_diag(
    const unsigned short* __restrict__ qb, const unsigned short* __restrict__ kb,
    const unsigned short* __restrict__ vT, const float* __restrict__ bias_emb,
    unsigned short* __restrict__ voutb)
{
    const int var = blockIdx.x, h = blockIdx.y, b = blockIdx.z;
    const int t = threadIdx.x, lane = t & 63, w = t >> 6;
    const int quad = lane >> 4, n16 = lane & 15;
    const int bh = b * 8 + h;
    const int m0 = var * 64 + w * 16;
    __shared__ unsigned short Pl[4 * 1280];
    unsigned short* Pw = &Pl[w * 1280];
    const int qoff = bh * 2048 * 64;
    const float scale = 0.125f;
    const float bias_same = bias_emb[8 + h];
    const int iloc = w * 16 + quad * 4;
    const int j0 = var * 64;

    short8 aq0 = *(const short8*)&qb[qoff + (m0 + n16) * 64 + quad * 8];
    short8 aq1 = *(const short8*)&qb[qoff + (m0 + n16) * 64 + 32 + quad * 8];

    f32x4 sc[4];
    #pragma unroll
    for (int nt = 0; nt < 4; nt++) {
        short8 k0f = *(const short8*)&kb[qoff + (j0 + nt * 16 + n16) * 64 + quad * 8];
        short8 k1f = *(const short8*)&kb[qoff + (j0 + nt * 16 + n16) * 64 + 32 + quad * 8];
        f32x4 s = {};
        s = MFMA16(aq0, k0f, s);
        s = MFMA16(aq1, k1f, s);
        sc[nt] = s;
    }
    float zl[4][4];
    #pragma unroll
    for (int nt = 0; nt < 4; nt++) {
        int jloc = nt * 16 + n16;
        #pragma unroll
        for (int r = 0; r < 4; r++) {
            float zz = scale * (sc[nt][r] + bias_same);
            if (jloc > iloc + r) zz = -1e30f;
            zl[nt][r] = zz;
        }
    }
    float cm[4], rsum[4], pr[4][4];
    #pragma unroll
    for (int r = 0; r < 4; r++)
        cm[r] = fmaxf(fmaxf(zl[0][r], zl[1][r]), fmaxf(zl[2][r], zl[3][r]));
    #pragma unroll
    for (int off = 1; off < 16; off <<= 1)
        #pragma unroll
        for (int r = 0; r < 4; r++)
            cm[r] = fmaxf(cm[r], __shfl_xor(cm[r], off));
    #pragma unroll
    for (int nt = 0; nt < 4; nt++)
        #pragma unroll
        for (int r = 0; r < 4; r++)
            pr[nt][r] = __expf(zl[nt][r] - cm[r]);
    #pragma unroll
    for (int r = 0; r < 4; r++)
        rsum[r] = (pr[0][r] + pr[1][r]) + (pr[2][r] + pr[3][r]);
    #pragma unroll
    for (int off = 1; off < 16; off <<= 1)
        #pragma unroll
        for (int r = 0; r < 4; r++)
            rsum[r] += __shfl_xor(rsum[r], off);
    #pragma unroll
    for (int nt = 0; nt < 4; nt++) {
        int s = nt >> 1, c = (nt & 1) * 16 + n16;
        #pragma unroll
        for (int r = 0; r < 4; r++)
            Pw[s * 640 + (quad * 4 + r) * 40 + c] = f2bf(pr[nt][r]);
    }
    short8 pa0 = *(const short8*)&Pw[0 * 640 + n16 * 40 + quad * 8];
    short8 pa1 = *(const short8*)&Pw[1 * 640 + n16 * 40 + quad * 8];
    f32x4 oacc[4] = {};
    #pragma unroll
    for (int et = 0; et < 4; et++) {
        const int vrow = (bh * 64 + et * 16 + n16) * 2048;
        short8 v0 = *(const short8*)&vT[vrow + j0 + quad * 8];
        short8 v1 = *(const short8*)&vT[vrow + j0 + 32 + quad * 8];
        oacc[et] = MFMA16(pa0, v0, oacc[et]);
        oacc[et] = MFMA16(pa1, v1, oacc[et]);
    }
    #pragma unroll
    for (int et = 0; et < 4; et++) {
        #pragma unroll
        for (int r = 0; r < 4; r++) {
            float o = oacc[et][r] / rsum[r];
            int l = m0 + quad * 4 + r;
            voutb[(b * 2048 + l) * 512 + h * 64 + et * 16 + n16] = f2bf(o);
        }
    }
}

// ---------------------------------------------------------------------------
// Kernel 4b: var-31 rows, split-flash. grid (split=8, h=8, b=2).
// Each block: 4 chunks (split*4 .. +3); chunk 31 is the causal diagonal.
// Emits unnormalized partial O (64x64 f32) + per-row m,l into scratch.
// ---------------------------------------------------------------------------
__global__ __launch_bounds__(256) void attn31(
    const unsigned short* __restrict__ qb, const unsigned short* __restrict__ kb,
    const unsigned short* __restrict__ vT, const float* __restrict__ bias_emb,
    float* __restrict__ Opart, float* __restrict__ Mp, float* __restrict__ Lp)
{
    const int split = blockIdx.x, h = blockIdx.y, b = blockIdx.z;
    const int t = threadIdx.x, lane = t & 63, w = t >> 6;
    const int quad = lane >> 4, n16 = lane & 15;
    const int bh = b * 8 + h;
    const int m0 = 31 * 64 + w * 16;
    __shared__ unsigned short Pl[4 * 1280];
    unsigned short* Pw = &Pl[w * 1280];
    const int qoff = bh * 2048 * 64;
    const float scale = 0.125f;
    const float bias_same = bias_emb[8 + h];
    const float bias_diff = bias_emb[h];
    const int iloc = w * 16 + quad * 4;

    short8 aq0 = *(const short8*)&qb[qoff + (m0 + n16) * 64 + quad * 8];
    short8 aq1 = *(const short8*)&qb[qoff + (m0 + n16) * 64 + 32 + quad * 8];

    f32x4 oacc[4] = {};
    float mrow[4], lrow[4];
    #pragma unroll
    for (int r = 0; r < 4; r++) { mrow[r] = -1e30f; lrow[r] = 0.f; }

    #pragma unroll
    for (int ci = 0; ci < 4; ci++) {
        const int chunk = split * 4 + ci;
        const bool diag = (chunk == 31);
        const float biasv = diag ? bias_same : bias_diff;
        const int j0 = chunk * 64;

        f32x4 sc[4];
        #pragma unroll
        for (int nt = 0; nt < 4; nt++) {
            short8 k0f = *(const short8*)&kb[qoff + (j0 + nt * 16 + n16) * 64 + quad * 8];
            short8 k1f = *(const short8*)&kb[qoff + (j0 + nt * 16 + n16) * 64 + 32 + quad * 8];
            f32x4 s = {};
            s = MFMA16(aq0, k0f, s);
            s = MFMA16(aq1, k1f, s);
            sc[nt] = s;
        }
        float zl[4][4];
        #pragma unroll
        for (int nt = 0; nt < 4; nt++) {
            int jloc = nt * 16 + n16;
            #pragma unroll
            for (int r = 0; r < 4; r++) {
                float zz = scale * (sc[nt][r] + biasv);
                if (diag && jloc > iloc + r) zz = -1e30f;
                zl[nt][r] = zz;
            }
        }
        float cm[4];
        #pragma unroll
        for (int r = 0; r < 4; r++)
            cm[r] = fmaxf(fmaxf(zl[0][r], zl[1][r]), fmaxf(zl[2][r], zl[3][r]));
        #pragma unroll
        for (int off = 1; off < 16; off <<= 1)
            #pragma unroll
            for (int r = 0; r < 4; r++)
                cm[r] = fmaxf(cm[r], __shfl_xor(cm[r], off));
        float mnew[4], alpha[4], rsum[4], pr[4][4];
        #pragma unroll
        for (int r = 0; r < 4; r++) {
            mnew[r] = fmaxf(mrow[r], cm[r]);
            alpha[r] = __expf(mrow[r] - mnew[r]);
        }
        #pragma unroll
        for (int nt = 0; nt < 4; nt++)
            #pragma unroll
            for (int r = 0; r < 4; r++)
                pr[nt][r] = __expf(zl[nt][r] - mnew[r]);
        #pragma unroll
        for (int r = 0; r < 4; r++)
            rsum[r] = (pr[0][r] + pr[1][r]) + (pr[2][r] + pr[3][r]);
        #pragma unroll
        for (int off = 1; off < 16; off <<= 1)
            #pragma unroll
            for (int r = 0; r < 4; r++)
                rsum[r] += __shfl_xor(rsum[r], off);
        #pragma unroll
        for (int r = 0; r < 4; r++) {
            lrow[r] = lrow[r] * alpha[r] + rsum[r];
            mrow[r] = mnew[r];
        }
        #pragma unroll
        for (int et = 0; et < 4; et++)
            #pragma unroll
            for (int r = 0; r < 4; r++)
                oacc[et][r] *= alpha[r];
        #pragma unroll
        for (int nt = 0; nt < 4; nt++) {
            int s = nt >> 1, c = (nt & 1) * 16 + n16;
            #pragma unroll
            for (int r = 0; r < 4; r++)
                Pw[s * 640 + (quad * 4 + r) * 40 + c] = f2bf(pr[nt][r]);
        }
        short8 pa0 = *(const short8*)&Pw[0 * 640 + n16 * 40 + quad * 8];
        short8 pa1 = *(const short8*)&Pw[1 * 640 + n16 * 40 + quad * 8];
        #pragma unroll
        for (int et = 0; et < 4; et++) {
            const int vrow = (bh * 64 + et * 16 + n16) * 2048;
            short8 v0 = *(const short8*)&vT[vrow + j0 + quad * 8];
            short8 v1 = *(const short8*)&vT[vrow + j0 + 32 + quad * 8];
            oacc[et] = MFMA16(pa0, v0, oacc[et]);
            oacc[et] = MFMA16(pa1, v1, oacc[et]);
        }
    }
    // partials: Opart[((bh*8+split)*64 + row)*64 + col]
    const int pb = (bh * 8 + split) * 64;
    #pragma unroll
    for (int et = 0; et < 4; et++)
        #pragma unroll
        for (int r = 0; r < 4; r++)
            Opart[(pb + w * 16 + quad * 4 + r) * 64 + et * 16 + n16] = oacc[et][r];
    if (n16 == 0) {
        #pragma unroll
        for (int r = 0; r < 4; r++) {
            Mp[pb + w * 16 + quad * 4 + r] = mrow[r];
            Lp[pb + w * 16 + quad * 4 + r] = lrow[r];
        }
    }
}

// ---------------------------------------------------------------------------
// Kernel 4c: merge 8 partials per (b,h). grid 16 blocks, 256 threads.
// thread -> row = t>>2, 16 cols = (t&3)*16.
// ---------------------------------------------------------------------------
__global__ __launch_bounds__(256) void attn31_merge(
    const float* __restrict__ Opart, const float* __restrict__ Mp,
    const float* __restrict__ Lp, unsigned short* __restrict__ voutb)
{
    const int bh = blockIdx.x, b = bh >> 3, h = bh & 7;
    const int t = threadIdx.x;
    const int row = t >> 2, c0 = (t & 3) * 16;
    float ms[8];
    float M = -1e30f;
    #pragma unroll
    for (int s = 0; s < 8; s++) {
        ms[s] = Mp[(bh * 8 + s) * 64 + row];
        M = fmaxf(M, ms[s]);
    }
    float L = 0.f;
    float es[8];
    #pragma unroll
    for (int s = 0; s < 8; s++) {
        es[s] = __expf(ms[s] - M);
        L += Lp[(bh * 8 + s) * 64 + row] * es[s];
    }
    float acc[16] = {};
    #pragma unroll
    for (int s = 0; s < 8; s++) {
        const float* op = &Opart[((bh * 8 + s) * 64 + row) * 64 + c0];
        #pragma unroll
        for (int k = 0; k < 4; k++) {
            float4 v = *(const float4*)&op[k * 4];
            acc[k*4+0] += v.x * es[s]; acc[k*4+1] += v.y * es[s];
            acc[k*4+2] += v.z * es[s]; acc[k*4+3] += v.w * es[s];
        }
    }
    const float inv = 1.f / L;
    const int l = 31 * 64 + row;
    u16x4 pk;
    #pragma unroll
    for (int k = 0; k < 4; k++) {
        pk[0] = f2bf(acc[k*4+0] * inv); pk[1] = f2bf(acc[k*4+1] * inv);
        pk[2] = f2bf(acc[k*4+2] * inv); pk[3] = f2bf(acc[k*4+3] * inv);
        *(u16x4*)&voutb[(b * 2048 + l) * 512 + h * 64 + c0 + k * 4] = pk;
    }
}

// ---------------------------------------------------------------------------
// Kernel 5: out = voutb(4096x512) @ Wo^T + bo  -> fp32 d_out
// ---------------------------------------------------------------------------
__global__ __launch_bounds__(256) void gemm_out(
    const unsigned short* __restrict__ ab, const unsigned short* __restrict__ wo,
    const float* __restrict__ bo, float* __restrict__ out)
{
    const int n0 = blockIdx.x * 128, m0 = blockIdx.y * 128;
    __shared__ unsigned short Al[128 * 40];
    __shared__ unsigned short Bl[128 * 40];
    const int t = threadIdx.x;
    const int lane = t & 63, w = t >> 6;
    const int wm = (w >> 1) * 64, wn = (w & 1) * 64;
    const int quad = lane >> 4, n16 = lane & 15;
    const int rs = t >> 2, cs = (t & 3) * 8;
    f32x4 acc[4][4] = {};
    for (int k0 = 0; k0 < 512; k0 += 32) {
        __syncthreads();
        *(short8*)&Al[rs * 40 + cs]        = *(const short8*)&ab[(m0 + rs) * 512 + k0 + cs];
        *(short8*)&Al[(rs + 64) * 40 + cs] = *(const short8*)&ab[(m0 + rs + 64) * 512 + k0 + cs];
        *(short8*)&Bl[rs * 40 + cs]        = *(const short8*)&wo[(n0 + rs) * 512 + k0 + cs];
        *(short8*)&Bl[(rs + 64) * 40 + cs] = *(const short8*)&wo[(n0 + rs + 64) * 512 + k0 + cs];
        __syncthreads();
        short8 af[4], bf[4];
        #pragma unroll
        for (int i = 0; i < 4; i++)
            af[i] = *(const short8*)&Al[(wm + i * 16 + n16) * 40 + quad * 8];
        #pragma unroll
        for (int i = 0; i < 4; i++)
            bf[i] = *(const short8*)&Bl[(wn + i * 16 + n16) * 40 + quad * 8];
        #pragma unroll
        for (int mi = 0; mi < 4; mi++)
            #pragma unroll
            for (int ni = 0; ni < 4; ni++)
                acc[mi][ni] = MFMA16(af[mi], bf[ni], acc[mi][ni]);
    }
    #pragma unroll
    for (int mi = 0; mi < 4; mi++) {
        #pragma unroll
        for (int ni = 0; ni < 4; ni++) {
            const int n = n0 + wn + ni * 16 + n16;
            const int mb = m0 + wm + mi * 16 + quad * 4;
            const float bias = bo[n];
            f32x4 v = acc[mi][ni];
            #pragma unroll
            for (int r = 0; r < 4; r++)
                out[(mb + r) * 512 + n] = v[r] + bias;
        }
    }
}

// ---------------------------------------------------------------------------
extern "C" void kernel_launch(void* const* d_in, const int* in_sizes, int n_in,
                              void* d_out, int out_size, void* d_ws, size_t ws_size,
                              hipStream_t stream)
{
    const float* x        = (const float*)d_in[0];
    const float* Wq       = (const float*)d_in[1];
    const float* bq       = (const float*)d_in[2];
    const float* Wk       = (const float*)d_in[3];
    const float* bk       = (const float*)d_in[4];
    const float* Wv       = (const float*)d_in[5];
    const float* bv       = (const float*)d_in[6];
    const float* Wo       = (const float*)d_in[7];
    const float* bo       = (const float*)d_in[8];
    const float* bias_emb = (const float*)d_in[9];

    unsigned short* xb  = (unsigned short*)d_ws;      // 2097152 elems (4 MB)
    unsigned short* wb  = xb + 2097152;               // 4 * 262144
    unsigned short* qb  = wb + 1048576;               // (B,H,L,E)
    unsigned short* kb  = qb + 2097152;               // (B,H,L,E)
    unsigned short* vT  = kb + 2097152;               // (B,H,E,L)
    unsigned short* vob = vT + 2097152;               // (B,L,H*E)

    // attn31 scratch reuses xb (dead after gemm_qkv):
    //   Opart: 16 bh * 8 splits * 64 * 64 f32 = 524288 floats (2 MB)
    //   Mp/Lp: 8192 floats each
    float* Opart = (float*)xb;
    float* Mp    = Opart + 524288;
    float* Lp    = Mp + 8192;

    hipLaunchKernelGGL(convertk, dim3(3072), dim3(256), 0, stream,
                       x, Wq, Wk, Wv, Wo, xb, wb);
    hipLaunchKernelGGL(gemm_qkv, dim3(4, 32, 3), dim3(256), 0, stream,
                       xb, wb, bq, bk, bv, qb, kb, vT);
    hipLaunchKernelGGL(ropek, dim3(4096), dim3(256), 0, stream, qb, kb);
    hipLaunchKernelGGL(attn_diag, dim3(31, 8, 2), dim3(256), 0, stream,
                       qb, kb, vT, bias_emb, vob);
    hipLaunchKernelGGL(attn31, dim3(8, 8, 2), dim3(256), 0, stream,
                       qb, kb, vT, bias_emb, Opart, Mp, Lp);
    hipLaunchKernelGGL(attn31_merge, dim3(16), dim3(256), 0, stream,
                       Opart, Mp, Lp, vob);
    hipLaunchKernelGGL(gemm_out, dim3(4, 32, 1), dim3(256), 0, stream,
                       vob, wb + 3 * 262144, bo, (float*)d_out);
}

// Round 3
// 135.392 us; speedup vs baseline: 1.8274x; 1.0409x over previous
//
#include <hip/hip_runtime.h>

typedef __attribute__((ext_vector_type(8))) short short8;
typedef __attribute__((ext_vector_type(4))) float f32x4;
typedef __attribute__((ext_vector_type(4))) unsigned short u16x4;

#define MFMA16(a, b, c) __builtin_amdgcn_mfma_f32_16x16x32_bf16(a, b, c, 0, 0, 0)

__device__ __forceinline__ unsigned short f2bf(float f) {
    union { float f; unsigned int u; } v; v.f = f;
    unsigned int r = (v.u + 0x7fffu + ((v.u >> 16) & 1u)) >> 16;
    return (unsigned short)r;
}

// ---------------------------------------------------------------------------
// Kernel 1: fp32 -> bf16 convert: x (2097152) then Wq,Wk,Wv,Wo (262144 each)
// ---------------------------------------------------------------------------
__global__ __launch_bounds__(256) void convertk(
    const float* __restrict__ x, const float* __restrict__ wq,
    const float* __restrict__ wk, const float* __restrict__ wv,
    const float* __restrict__ wo, unsigned short* __restrict__ xb,
    unsigned short* __restrict__ wb)
{
    int i = (blockIdx.x * 256 + threadIdx.x) * 4;
    const float* src;
    unsigned short* dst;
    if (i < 2097152) { src = x + i; dst = xb + i; }
    else {
        int j = i - 2097152;
        int w = j >> 18;
        int o = j & 262143;
        src = (w == 0 ? wq : w == 1 ? wk : w == 2 ? wv : wo) + o;
        dst = wb + j;
    }
    float4 v = *(const float4*)src;
    u16x4 p;
    p[0] = f2bf(v.x); p[1] = f2bf(v.y); p[2] = f2bf(v.z); p[3] = f2bf(v.w);
    *(u16x4*)dst = p;
}

// ---------------------------------------------------------------------------
// Kernel 2: QKV GEMM with fused RoPE epilogue for q,k.
// C[m,n] = sum_k xb[m,k]*W[n,k] + bias[n]; z=0:q, 1:k -> (B,H,L,E) with RoPE
// applied to dims e<32 (pair (2j,2j+1), angle l*10000^(-j/16)); z=2:v ->
// transposed (B,H,E,L).  RoPE pair partner lives in lane n16^1 -> shfl_xor.
// ---------------------------------------------------------------------------
__global__ __launch_bounds__(256) void gemm_qkv(
    const unsigned short* __restrict__ xb, const unsigned short* __restrict__ wb,
    const float* __restrict__ bq, const float* __restrict__ bk,
    const float* __restrict__ bv,
    unsigned short* __restrict__ qb, unsigned short* __restrict__ kb,
    unsigned short* __restrict__ vT)
{
    const int z = blockIdx.z;
    const unsigned short* Wz = wb + z * 262144;
    const int n0 = blockIdx.x * 128, m0 = blockIdx.y * 128;
    __shared__ unsigned short Al[128 * 40];
    __shared__ unsigned short Bl[128 * 40];
    const int t = threadIdx.x;
    const int lane = t & 63, w = t >> 6;
    const int wm = (w >> 1) * 64, wn = (w & 1) * 64;
    const int quad = lane >> 4, n16 = lane & 15;
    const int rs = t >> 2, cs = (t & 3) * 8;
    f32x4 acc[4][4] = {};
    for (int k0 = 0; k0 < 512; k0 += 32) {
        __syncthreads();
        *(short8*)&Al[rs * 40 + cs]        = *(const short8*)&xb[(m0 + rs) * 512 + k0 + cs];
        *(short8*)&Al[(rs + 64) * 40 + cs] = *(const short8*)&xb[(m0 + rs + 64) * 512 + k0 + cs];
        *(short8*)&Bl[rs * 40 + cs]        = *(const short8*)&Wz[(n0 + rs) * 512 + k0 + cs];
        *(short8*)&Bl[(rs + 64) * 40 + cs] = *(const short8*)&Wz[(n0 + rs + 64) * 512 + k0 + cs];
        __syncthreads();
        short8 af[4], bf[4];
        #pragma unroll
        for (int i = 0; i < 4; i++)
            af[i] = *(const short8*)&Al[(wm + i * 16 + n16) * 40 + quad * 8];
        #pragma unroll
        for (int i = 0; i < 4; i++)
            bf[i] = *(const short8*)&Bl[(wn + i * 16 + n16) * 40 + quad * 8];
        #pragma unroll
        for (int mi = 0; mi < 4; mi++)
            #pragma unroll
            for (int ni = 0; ni < 4; ni++)
                acc[mi][ni] = MFMA16(af[mi], bf[ni], acc[mi][ni]);
    }
    const float* bias_p = (z == 0) ? bq : (z == 1) ? bk : bv;
    unsigned short* dst01 = (z == 0) ? qb : kb;
    #pragma unroll
    for (int mi = 0; mi < 4; mi++) {
        #pragma unroll
        for (int ni = 0; ni < 4; ni++) {
            const int n = n0 + wn + ni * 16 + n16;
            const int mb = m0 + wm + mi * 16 + quad * 4;
            const float bias = bias_p[n];
            const int h = n >> 6, e_lo = ni * 16 + n16;   // = n & 63 (wn is 0 or 64)
            f32x4 v = acc[mi][ni];
            if (z < 2) {
                float vr[4];
                #pragma unroll
                for (int r = 0; r < 4; r++) vr[r] = v[r] + bias;
                if (ni < 2) {   // e < 32: RoPE (uniform branch: ni compile-time)
                    const int j = e_lo >> 1;
                    const float theta = exp2f(-(float)j * 0.8304820237218405f); // log2(1e4)/16
                    #pragma unroll
                    for (int r = 0; r < 4; r++) {
                        int l = (mb + r) & 2047;
                        float s, c;
                        __sincosf((float)l * theta, &s, &c);
                        float p = __shfl_xor(vr[r], 1);
                        vr[r] = (e_lo & 1) ? (c * vr[r] + s * p) : (c * vr[r] - s * p);
                    }
                }
                #pragma unroll
                for (int r = 0; r < 4; r++) {
                    int m = mb + r, b = m >> 11, l = m & 2047;
                    dst01[((b * 8 + h) * 2048 + l) * 64 + e_lo] = f2bf(vr[r]);
                }
            } else {
                int b = mb >> 11, l = mb & 2047;
                u16x4 pk;
                #pragma unroll
                for (int r = 0; r < 4; r++) pk[r] = f2bf(v[r] + bias);
                *(u16x4*)&vT[((b * 8 + h) * 64 + e_lo) * 2048 + l] = pk;
            }
        }
    }
}

// ---------------------------------------------------------------------------
// Kernel 3: combined attention. grid (39, 8, 2).
//   blockIdx.x < 31 : diagonal var = x (one-pass softmax, single chunk)
//   blockIdx.x >= 31: var-31 split s = x-31, 4 chunks, emits partials.
// No barriers: per-wave-private P LDS, within-wave lgkmcnt ordering.
// ---------------------------------------------------------------------------
__global__ __launch_bounds__(256) void attn_all(
    const unsigned short* __restrict__ qb, const unsigned short* __restrict__ kb,
    const unsigned short* __restrict__ vT, const float* __restrict__ bias_emb,
    unsigned short* __restrict__ voutb,
    float* __restrict__ Opart, float* __restrict__ Mp, float* __restrict__ Lp)
{
    const int xid = blockIdx.x, h = blockIdx.y, b = blockIdx.z;
    const int t = threadIdx.x, lane = t & 63, w = t >> 6;
    const int quad = lane >> 4, n16 = lane & 15;
    const int bh = b * 8 + h;
    __shared__ unsigned short Pl[4 * 1280];
    unsigned short* Pw = &Pl[w * 1280];
    const int qoff = bh * 2048 * 64;
    const float scale = 0.125f;
    const float bias_same = bias_emb[8 + h];
    const int iloc = w * 16 + quad * 4;

    if (xid < 31) {
        const int var = xid;
        const int m0 = var * 64 + w * 16;
        const int j0 = var * 64;
        short8 aq0 = *(const short8*)&qb[qoff + (m0 + n16) * 64 + quad * 8];
        short8 aq1 = *(const short8*)&qb[qoff + (m0 + n16) * 64 + 32 + quad * 8];
        f32x4 sc[4];
        #pragma unroll
        for (int nt = 0; nt < 4; nt++) {
            short8 k0f = *(const short8*)&kb[qoff + (j0 + nt * 16 + n16) * 64 + quad * 8];
            short8 k1f = *(const short8*)&kb[qoff + (j0 + nt * 16 + n16) * 64 + 32 + quad * 8];
            f32x4 s = {};
            s = MFMA16(aq0, k0f, s);
            s = MFMA16(aq1, k1f, s);
            sc[nt] = s;
        }
        float zl[4][4];
        #pragma unroll
        for (int nt = 0; nt < 4; nt++) {
            int jloc = nt * 16 + n16;
            #pragma unroll
            for (int r = 0; r < 4; r++) {
                float zz = scale * (sc[nt][r] + bias_same);
                if (jloc > iloc + r) zz = -1e30f;
                zl[nt][r] = zz;
            }
        }
        float cm[4], rsum[4], pr[4][4];
        #pragma unroll
        for (int r = 0; r < 4; r++)
            cm[r] = fmaxf(fmaxf(zl[0][r], zl[1][r]), fmaxf(zl[2][r], zl[3][r]));
        #pragma unroll
        for (int off = 1; off < 16; off <<= 1)
            #pragma unroll
            for (int r = 0; r < 4; r++)
                cm[r] = fmaxf(cm[r], __shfl_xor(cm[r], off));
        #pragma unroll
        for (int nt = 0; nt < 4; nt++)
            #pragma unroll
            for (int r = 0; r < 4; r++)
                pr[nt][r] = __expf(zl[nt][r] - cm[r]);
        #pragma unroll
        for (int r = 0; r < 4; r++)
            rsum[r] = (pr[0][r] + pr[1][r]) + (pr[2][r] + pr[3][r]);
        #pragma unroll
        for (int off = 1; off < 16; off <<= 1)
            #pragma unroll
            for (int r = 0; r < 4; r++)
                rsum[r] += __shfl_xor(rsum[r], off);
        #pragma unroll
        for (int nt = 0; nt < 4; nt++) {
            int s = nt >> 1, c = (nt & 1) * 16 + n16;
            #pragma unroll
            for (int r = 0; r < 4; r++)
                Pw[s * 640 + (quad * 4 + r) * 40 + c] = f2bf(pr[nt][r]);
        }
        short8 pa0 = *(const short8*)&Pw[0 * 640 + n16 * 40 + quad * 8];
        short8 pa1 = *(const short8*)&Pw[1 * 640 + n16 * 40 + quad * 8];
        f32x4 oacc[4] = {};
        #pragma unroll
        for (int et = 0; et < 4; et++) {
            const int vrow = (bh * 64 + et * 16 + n16) * 2048;
            short8 v0 = *(const short8*)&vT[vrow + j0 + quad * 8];
            short8 v1 = *(const short8*)&vT[vrow + j0 + 32 + quad * 8];
            oacc[et] = MFMA16(pa0, v0, oacc[et]);
            oacc[et] = MFMA16(pa1, v1, oacc[et]);
        }
        #pragma unroll
        for (int et = 0; et < 4; et++) {
            #pragma unroll
            for (int r = 0; r < 4; r++) {
                float o = oacc[et][r] / rsum[r];
                int l = m0 + quad * 4 + r;
                voutb[(b * 2048 + l) * 512 + h * 64 + et * 16 + n16] = f2bf(o);
            }
        }
    } else {
        const int split = xid - 31;
        const int m0 = 31 * 64 + w * 16;
        const float bias_diff = bias_emb[h];
        short8 aq0 = *(const short8*)&qb[qoff + (m0 + n16) * 64 + quad * 8];
        short8 aq1 = *(const short8*)&qb[qoff + (m0 + n16) * 64 + 32 + quad * 8];
        f32x4 oacc[4] = {};
        float mrow[4], lrow[4];
        #pragma unroll
        for (int r = 0; r < 4; r++) { mrow[r] = -1e30f; lrow[r] = 0.f; }
        #pragma unroll
        for (int ci = 0; ci < 4; ci++) {
            const int chunk = split * 4 + ci;
            const bool diag = (chunk == 31);
            const float biasv = diag ? bias_same : bias_diff;
            const int j0 = chunk * 64;
            f32x4 sc[4];
            #pragma unroll
            for (int nt = 0; nt < 4; nt++) {
                short8 k0f = *(const short8*)&kb[qoff + (j0 + nt * 16 + n16) * 64 + quad * 8];
                short8 k1f = *(const short8*)&kb[qoff + (j0 + nt * 16 + n16) * 64 + 32 + quad * 8];
                f32x4 s = {};
                s = MFMA16(aq0, k0f, s);
                s = MFMA16(aq1, k1f, s);
                sc[nt] = s;
            }
            float zl[4][4];
            #pragma unroll
            for (int nt = 0; nt < 4; nt++) {
                int jloc = nt * 16 + n16;
                #pragma unroll
                for (int r = 0; r < 4; r++) {
                    float zz = scale * (sc[nt][r] + biasv);
                    if (diag && jloc > iloc + r) zz = -1e30f;
                    zl[nt][r] = zz;
                }
            }
            float cm[4];
            #pragma unroll
            for (int r = 0; r < 4; r++)
                cm[r] = fmaxf(fmaxf(zl[0][r], zl[1][r]), fmaxf(zl[2][r], zl[3][r]));
            #pragma unroll
            for (int off = 1; off < 16; off <<= 1)
                #pragma unroll
                for (int r = 0; r < 4; r++)
                    cm[r] = fmaxf(cm[r], __shfl_xor(cm[r], off));
            float mnew[4], alpha[4], rsum[4], pr[4][4];
            #pragma unroll
            for (int r = 0; r < 4; r++) {
                mnew[r] = fmaxf(mrow[r], cm[r]);
                alpha[r] = __expf(mrow[r] - mnew[r]);
            }
            #pragma unroll
            for (int nt = 0; nt < 4; nt++)
                #pragma unroll
                for (int r = 0; r < 4; r++)
                    pr[nt][r] = __expf(zl[nt][r] - mnew[r]);
            #pragma unroll
            for (int r = 0; r < 4; r++)
                rsum[r] = (pr[0][r] + pr[1][r]) + (pr[2][r] + pr[3][r]);
            #pragma unroll
            for (int off = 1; off < 16; off <<= 1)
                #pragma unroll
                for (int r = 0; r < 4; r++)
                    rsum[r] += __shfl_xor(rsum[r], off);
            #pragma unroll
            for (int r = 0; r < 4; r++) {
                lrow[r] = lrow[r] * alpha[r] + rsum[r];
                mrow[r] = mnew[r];
            }
            #pragma unroll
            for (int et = 0; et < 4; et++)
                #pragma unroll
                for (int r = 0; r < 4; r++)
                    oacc[et][r] *= alpha[r];
            #pragma unroll
            for (int nt = 0; nt < 4; nt++) {
                int s = nt >> 1, c = (nt & 1) * 16 + n16;
                #pragma unroll
                for (int r = 0; r < 4; r++)
                    Pw[s * 640 + (quad * 4 + r) * 40 + c] = f2bf(pr[nt][r]);
            }
            short8 pa0 = *(const short8*)&Pw[0 * 640 + n16 * 40 + quad * 8];
            short8 pa1 = *(const short8*)&Pw[1 * 640 + n16 * 40 + quad * 8];
            #pragma unroll
            for (int et = 0; et < 4; et++) {
                const int vrow = (bh * 64 + et * 16 + n16) * 2048;
                short8 v0 = *(const short8*)&vT[vrow + j0 + quad * 8];
                short8 v1 = *(const short8*)&vT[vrow + j0 + 32 + quad * 8];
                oacc[et] = MFMA16(pa0, v0, oacc[et]);
                oacc[et] = MFMA16(pa1, v1, oacc[et]);
            }
        }
        const int pb = (bh * 8 + split) * 64;
        #pragma unroll
        for (int et = 0; et < 4; et++)
            #pragma unroll
            for (int r = 0; r < 4; r++)
                Opart[(pb + w * 16 + quad * 4 + r) * 64 + et * 16 + n16] = oacc[et][r];
        if (n16 == 0) {
            #pragma unroll
            for (int r = 0; r < 4; r++) {
                Mp[pb + w * 16 + quad * 4 + r] = mrow[r];
                Lp[pb + w * 16 + quad * 4 + r] = lrow[r];
            }
        }
    }
}

// ---------------------------------------------------------------------------
// Kernel 4: merge 8 partials per (b,h). grid 16 blocks, 256 threads.
// ---------------------------------------------------------------------------
__global__ __launch_bounds__(256) void attn31_merge(
    const float* __restrict__ Opart, const float* __restrict__ Mp,
    const float* __restrict__ Lp, unsigned short* __restrict__ voutb)
{
    const int bh = blockIdx.x, b = bh >> 3, h = bh & 7;
    const int t = threadIdx.x;
    const int row = t >> 2, c0 = (t & 3) * 16;
    float ms[8];
    float M = -1e30f;
    #pragma unroll
    for (int s = 0; s < 8; s++) {
        ms[s] = Mp[(bh * 8 + s) * 64 + row];
        M = fmaxf(M, ms[s]);
    }
    float L = 0.f;
    float es[8];
    #pragma unroll
    for (int s = 0; s < 8; s++) {
        es[s] = __expf(ms[s] - M);
        L += Lp[(bh * 8 + s) * 64 + row] * es[s];
    }
    float acc[16] = {};
    #pragma unroll
    for (int s = 0; s < 8; s++) {
        const float* op = &Opart[((bh * 8 + s) * 64 + row) * 64 + c0];
        #pragma unroll
        for (int k = 0; k < 4; k++) {
            float4 v = *(const float4*)&op[k * 4];
            acc[k*4+0] += v.x * es[s]; acc[k*4+1] += v.y * es[s];
            acc[k*4+2] += v.z * es[s]; acc[k*4+3] += v.w * es[s];
        }
    }
    const float inv = 1.f / L;
    const int l = 31 * 64 + row;
    u16x4 pk;
    #pragma unroll
    for (int k = 0; k < 4; k++) {
        pk[0] = f2bf(acc[k*4+0] * inv); pk[1] = f2bf(acc[k*4+1] * inv);
        pk[2] = f2bf(acc[k*4+2] * inv); pk[3] = f2bf(acc[k*4+3] * inv);
        *(u16x4*)&voutb[(b * 2048 + l) * 512 + h * 64 + c0 + k * 4] = pk;
    }
}

// ---------------------------------------------------------------------------
// Kernel 5: out = voutb(4096x512) @ Wo^T + bo  -> fp32 d_out
// ---------------------------------------------------------------------------
__global__ __launch_bounds__(256) void gemm_out(
    const unsigned short* __restrict__ ab, const unsigned short* __restrict__ wo,
    const float* __restrict__ bo, float* __restrict__ out)
{
    const int n0 = blockIdx.x * 128, m0 = blockIdx.y * 128;
    __shared__ unsigned short Al[128 * 40];
    __shared__ unsigned short Bl[128 * 40];
    const int t = threadIdx.x;
    const int lane = t & 63, w = t >> 6;
    const int wm = (w >> 1) * 64, wn = (w & 1) * 64;
    const int quad = lane >> 4, n16 = lane & 15;
    const int rs = t >> 2, cs = (t & 3) * 8;
    f32x4 acc[4][4] = {};
    for (int k0 = 0; k0 < 512; k0 += 32) {
        __syncthreads();
        *(short8*)&Al[rs * 40 + cs]        = *(const short8*)&ab[(m0 + rs) * 512 + k0 + cs];
        *(short8*)&Al[(rs + 64) * 40 + cs] = *(const short8*)&ab[(m0 + rs + 64) * 512 + k0 + cs];
        *(short8*)&Bl[rs * 40 + cs]        = *(const short8*)&wo[(n0 + rs) * 512 + k0 + cs];
        *(short8*)&Bl[(rs + 64) * 40 + cs] = *(const short8*)&wo[(n0 + rs + 64) * 512 + k0 + cs];
        __syncthreads();
        short8 af[4], bf[4];
        #pragma unroll
        for (int i = 0; i < 4; i++)
            af[i] = *(const short8*)&Al[(wm + i * 16 + n16) * 40 + quad * 8];
        #pragma unroll
        for (int i = 0; i < 4; i++)
            bf[i] = *(const short8*)&Bl[(wn + i * 16 + n16) * 40 + quad * 8];
        #pragma unroll
        for (int mi = 0; mi < 4; mi++)
            #pragma unroll
            for (int ni = 0; ni < 4; ni++)
                acc[mi][ni] = MFMA16(af[mi], bf[ni], acc[mi][ni]);
    }
    #pragma unroll
    for (int mi = 0; mi < 4; mi++) {
        #pragma unroll
        for (int ni = 0; ni < 4; ni++) {
            const int n = n0 + wn + ni * 16 + n16;
            const int mb = m0 + wm + mi * 16 + quad * 4;
            const float bias = bo[n];
            f32x4 v = acc[mi][ni];
            #pragma unroll
            for (int r = 0; r < 4; r++)
                out[(mb + r) * 512 + n] = v[r] + bias;
        }
    }
}

// ---------------------------------------------------------------------------
extern "C" void kernel_launch(void* const* d_in, const int* in_sizes, int n_in,
                              void* d_out, int out_size, void* d_ws, size_t ws_size,
                              hipStream_t stream)
{
    const float* x        = (const float*)d_in[0];
    const float* Wq       = (const float*)d_in[1];
    const float* bq       = (const float*)d_in[2];
    const float* Wk       = (const float*)d_in[3];
    const float* bk       = (const float*)d_in[4];
    const float* Wv       = (const float*)d_in[5];
    const float* bv       = (const float*)d_in[6];
    const float* Wo       = (const float*)d_in[7];
    const float* bo       = (const float*)d_in[8];
    const float* bias_emb = (const float*)d_in[9];

    unsigned short* xb  = (unsigned short*)d_ws;      // 2097152 elems (4 MB)
    unsigned short* wb  = xb + 2097152;               // 4 * 262144
    unsigned short* qb  = wb + 1048576;               // (B,H,L,E)
    unsigned short* kb  = qb + 2097152;               // (B,H,L,E)
    unsigned short* vT  = kb + 2097152;               // (B,H,E,L)
    unsigned short* vob = vT + 2097152;               // (B,L,H*E)

    // attn31 scratch reuses xb (dead after gemm_qkv)
    float* Opart = (float*)xb;
    float* Mp    = Opart + 524288;
    float* Lp    = Mp + 8192;

    hipLaunchKernelGGL(convertk, dim3(3072), dim3(256), 0, stream,
                       x, Wq, Wk, Wv, Wo, xb, wb);
    hipLaunchKernelGGL(gemm_qkv, dim3(4, 32, 3), dim3(256), 0, stream,
                       xb, wb, bq, bk, bv, qb, kb, vT);
    hipLaunchKernelGGL(attn_all, dim3(39, 8, 2), dim3(256), 0, stream,
                       qb, kb, vT, bias_emb, vob, Opart, Mp, Lp);
    hipLaunchKernelGGL(attn31_merge, dim3(16), dim3(256), 0, stream,
                       Opart, Mp, Lp, vob);
    hipLaunchKernelGGL(gemm_out, dim3(4, 32, 1), dim3(256), 0, stream,
                       vob, wb + 3 * 262144, bo, (float*)d_out);
}

// Round 4
// 132.089 us; speedup vs baseline: 1.8731x; 1.0250x over previous
//
#include <hip/hip_runtime.h>

typedef __attribute__((ext_vector_type(8))) short short8;
typedef __attribute__((ext_vector_type(4))) float f32x4;
typedef __attribute__((ext_vector_type(4))) unsigned short u16x4;

#define MFMA16(a, b, c) __builtin_amdgcn_mfma_f32_16x16x32_bf16(a, b, c, 0, 0, 0)

// global_load_lds: per-lane 16B from global -> wave-uniform LDS base + lane*16
#define GLD16(gp, lp) __builtin_amdgcn_global_load_lds( \
    (const __attribute__((address_space(1))) unsigned int*)(gp), \
    (__attribute__((address_space(3))) unsigned int*)(lp), 16, 0, 0)

__device__ __forceinline__ unsigned short f2bf(float f) {
    union { float f; unsigned int u; } v; v.f = f;
    unsigned int r = (v.u + 0x7fffu + ((v.u >> 16) & 1u)) >> 16;
    return (unsigned short)r;
}

// ---------------------------------------------------------------------------
// Kernel 1: fp32 -> bf16 convert: x (2097152) then Wq,Wk,Wv,Wo (262144 each)
// ---------------------------------------------------------------------------
__global__ __launch_bounds__(256) void convertk(
    const float* __restrict__ x, const float* __restrict__ wq,
    const float* __restrict__ wk, const float* __restrict__ wv,
    const float* __restrict__ wo, unsigned short* __restrict__ xb,
    unsigned short* __restrict__ wb)
{
    int i = (blockIdx.x * 256 + threadIdx.x) * 4;
    const float* src;
    unsigned short* dst;
    if (i < 2097152) { src = x + i; dst = xb + i; }
    else {
        int j = i - 2097152;
        int w = j >> 18;
        int o = j & 262143;
        src = (w == 0 ? wq : w == 1 ? wk : w == 2 ? wv : wo) + o;
        dst = wb + j;
    }
    float4 v = *(const float4*)src;
    u16x4 p;
    p[0] = f2bf(v.x); p[1] = f2bf(v.y); p[2] = f2bf(v.z); p[3] = f2bf(v.w);
    *(u16x4*)dst = p;
}

// ---------------------------------------------------------------------------
// Kernel 2: QKV GEMM with fused RoPE epilogue.  Staging via global_load_lds
// (16B/lane, lane-contiguous LDS groups of 16 rows x 32 cols) with XOR
// column-block swizzle so fragment ds_read_b128 is 2-way (free) on banks:
//   stage: lane fetches global col-block (lane&3)^((row>>1)&3)
//   read : lane (n16,quad) reads slot quad^((n16>>1)&3)
// ---------------------------------------------------------------------------
__global__ __launch_bounds__(256) void gemm_qkv(
    const unsigned short* __restrict__ xb, const unsigned short* __restrict__ wb,
    const float* __restrict__ bq, const float* __restrict__ bk,
    const float* __restrict__ bv,
    unsigned short* __restrict__ qb, unsigned short* __restrict__ kb,
    unsigned short* __restrict__ vT)
{
    const int z = blockIdx.z;
    const unsigned short* Wz = wb + z * 262144;
    const int n0 = blockIdx.x * 128, m0 = blockIdx.y * 128;
    __shared__ unsigned short Al[128 * 32];
    __shared__ unsigned short Bl[128 * 32];
    const int t = threadIdx.x;
    const int lane = t & 63, w = t >> 6;
    const int wm = (w >> 1) * 64, wn = (w & 1) * 64;
    const int quad = lane >> 4, n16 = lane & 15;
    const int rA = lane >> 2;                               // row within 16-row group
    const int cG = (((lane & 3) ^ ((rA >> 1) & 3))) * 8;    // swizzled global col-block
    const int slotq = (quad ^ ((n16 >> 1) & 3)) * 8;        // swizzled LDS frag slot
    const int fragA = (wm >> 4) * 512 + n16 * 32 + slotq;   // group*512 + row*32 + slot
    const int fragB = (wn >> 4) * 512 + n16 * 32 + slotq;
    f32x4 acc[4][4] = {};
    for (int k0 = 0; k0 < 512; k0 += 32) {
        __syncthreads();
        #pragma unroll
        for (int i = 0; i < 2; i++) {
            const int row = w * 32 + i * 16;                // group base row
            GLD16(&xb[(m0 + row + rA) * 512 + k0 + cG], &Al[row * 32]);
            GLD16(&Wz[(n0 + row + rA) * 512 + k0 + cG], &Bl[row * 32]);
        }
        __syncthreads();
        short8 af[4], bfr[4];
        #pragma unroll
        for (int i = 0; i < 4; i++) af[i]  = *(const short8*)&Al[fragA + i * 512];
        #pragma unroll
        for (int i = 0; i < 4; i++) bfr[i] = *(const short8*)&Bl[fragB + i * 512];
        #pragma unroll
        for (int mi = 0; mi < 4; mi++)
            #pragma unroll
            for (int ni = 0; ni < 4; ni++)
                acc[mi][ni] = MFMA16(af[mi], bfr[ni], acc[mi][ni]);
    }
    const float* bias_p = (z == 0) ? bq : (z == 1) ? bk : bv;
    unsigned short* dst01 = (z == 0) ? qb : kb;
    #pragma unroll
    for (int mi = 0; mi < 4; mi++) {
        #pragma unroll
        for (int ni = 0; ni < 4; ni++) {
            const int n = n0 + wn + ni * 16 + n16;
            const int mb = m0 + wm + mi * 16 + quad * 4;
            const float bias = bias_p[n];
            const int h = n >> 6, e_lo = ni * 16 + n16;
            f32x4 v = acc[mi][ni];
            if (z < 2) {
                float vr[4];
                #pragma unroll
                for (int r = 0; r < 4; r++) vr[r] = v[r] + bias;
                if (ni < 2) {   // e < 32: RoPE
                    const int j = e_lo >> 1;
                    const float theta = exp2f(-(float)j * 0.8304820237218405f);
                    #pragma unroll
                    for (int r = 0; r < 4; r++) {
                        int l = (mb + r) & 2047;
                        float s, c;
                        __sincosf((float)l * theta, &s, &c);
                        float p = __shfl_xor(vr[r], 1);
                        vr[r] = (e_lo & 1) ? (c * vr[r] + s * p) : (c * vr[r] - s * p);
                    }
                }
                #pragma unroll
                for (int r = 0; r < 4; r++) {
                    int m = mb + r, b = m >> 11, l = m & 2047;
                    dst01[((b * 8 + h) * 2048 + l) * 64 + e_lo] = f2bf(vr[r]);
                }
            } else {
                int b = mb >> 11, l = mb & 2047;
                u16x4 pk;
                #pragma unroll
                for (int r = 0; r < 4; r++) pk[r] = f2bf(v[r] + bias);
                *(u16x4*)&vT[((b * 8 + h) * 64 + e_lo) * 2048 + l] = pk;
            }
        }
    }
}

// ---------------------------------------------------------------------------
// Kernel 3: combined attention. grid (39, 8, 2).
//   blockIdx.x < 31 : diagonal var = x (one-pass softmax, single chunk)
//   blockIdx.x >= 31: var-31 split s = x-31, 4 chunks, emits partials.
// ---------------------------------------------------------------------------
__global__ __launch_bounds__(256) void attn_all(
    const unsigned short* __restrict__ qb, const unsigned short* __restrict__ kb,
    const unsigned short* __restrict__ vT, const float* __restrict__ bias_emb,
    unsigned short* __restrict__ voutb,
    float* __restrict__ Opart, float* __restrict__ Mp, float* __restrict__ Lp)
{
    const int xid = blockIdx.x, h = blockIdx.y, b = blockIdx.z;
    const int t = threadIdx.x, lane = t & 63, w = t >> 6;
    const int quad = lane >> 4, n16 = lane & 15;
    const int bh = b * 8 + h;
    __shared__ unsigned short Pl[4 * 1280];
    unsigned short* Pw = &Pl[w * 1280];
    const int qoff = bh * 2048 * 64;
    const float scale = 0.125f;
    const float bias_same = bias_emb[8 + h];
    const int iloc = w * 16 + quad * 4;

    if (xid < 31) {
        const int var = xid;
        const int m0 = var * 64 + w * 16;
        const int j0 = var * 64;
        short8 aq0 = *(const short8*)&qb[qoff + (m0 + n16) * 64 + quad * 8];
        short8 aq1 = *(const short8*)&qb[qoff + (m0 + n16) * 64 + 32 + quad * 8];
        f32x4 sc[4];
        #pragma unroll
        for (int nt = 0; nt < 4; nt++) {
            short8 k0f = *(const short8*)&kb[qoff + (j0 + nt * 16 + n16) * 64 + quad * 8];
            short8 k1f = *(const short8*)&kb[qoff + (j0 + nt * 16 + n16) * 64 + 32 + quad * 8];
            f32x4 s = {};
            s = MFMA16(aq0, k0f, s);
            s = MFMA16(aq1, k1f, s);
            sc[nt] = s;
        }
        float zl[4][4];
        #pragma unroll
        for (int nt = 0; nt < 4; nt++) {
            int jloc = nt * 16 + n16;
            #pragma unroll
            for (int r = 0; r < 4; r++) {
                float zz = scale * (sc[nt][r] + bias_same);
                if (jloc > iloc + r) zz = -1e30f;
                zl[nt][r] = zz;
            }
        }
        float cm[4], rsum[4], pr[4][4];
        #pragma unroll
        for (int r = 0; r < 4; r++)
            cm[r] = fmaxf(fmaxf(zl[0][r], zl[1][r]), fmaxf(zl[2][r], zl[3][r]));
        #pragma unroll
        for (int off = 1; off < 16; off <<= 1)
            #pragma unroll
            for (int r = 0; r < 4; r++)
                cm[r] = fmaxf(cm[r], __shfl_xor(cm[r], off));
        #pragma unroll
        for (int nt = 0; nt < 4; nt++)
            #pragma unroll
            for (int r = 0; r < 4; r++)
                pr[nt][r] = __expf(zl[nt][r] - cm[r]);
        #pragma unroll
        for (int r = 0; r < 4; r++)
            rsum[r] = (pr[0][r] + pr[1][r]) + (pr[2][r] + pr[3][r]);
        #pragma unroll
        for (int off = 1; off < 16; off <<= 1)
            #pragma unroll
            for (int r = 0; r < 4; r++)
                rsum[r] += __shfl_xor(rsum[r], off);
        #pragma unroll
        for (int nt = 0; nt < 4; nt++) {
            int s = nt >> 1, c = (nt & 1) * 16 + n16;
            #pragma unroll
            for (int r = 0; r < 4; r++)
                Pw[s * 640 + (quad * 4 + r) * 40 + c] = f2bf(pr[nt][r]);
        }
        short8 pa0 = *(const short8*)&Pw[0 * 640 + n16 * 40 + quad * 8];
        short8 pa1 = *(const short8*)&Pw[1 * 640 + n16 * 40 + quad * 8];
        f32x4 oacc[4] = {};
        #pragma unroll
        for (int et = 0; et < 4; et++) {
            const int vrow = (bh * 64 + et * 16 + n16) * 2048;
            short8 v0 = *(const short8*)&vT[vrow + j0 + quad * 8];
            short8 v1 = *(const short8*)&vT[vrow + j0 + 32 + quad * 8];
            oacc[et] = MFMA16(pa0, v0, oacc[et]);
            oacc[et] = MFMA16(pa1, v1, oacc[et]);
        }
        #pragma unroll
        for (int et = 0; et < 4; et++) {
            #pragma unroll
            for (int r = 0; r < 4; r++) {
                float o = oacc[et][r] / rsum[r];
                int l = m0 + quad * 4 + r;
                voutb[(b * 2048 + l) * 512 + h * 64 + et * 16 + n16] = f2bf(o);
            }
        }
    } else {
        const int split = xid - 31;
        const int m0 = 31 * 64 + w * 16;
        const float bias_diff = bias_emb[h];
        short8 aq0 = *(const short8*)&qb[qoff + (m0 + n16) * 64 + quad * 8];
        short8 aq1 = *(const short8*)&qb[qoff + (m0 + n16) * 64 + 32 + quad * 8];
        f32x4 oacc[4] = {};
        float mrow[4], lrow[4];
        #pragma unroll
        for (int r = 0; r < 4; r++) { mrow[r] = -1e30f; lrow[r] = 0.f; }
        #pragma unroll
        for (int ci = 0; ci < 4; ci++) {
            const int chunk = split * 4 + ci;
            const bool diag = (chunk == 31);
            const float biasv = diag ? bias_same : bias_diff;
            const int j0 = chunk * 64;
            f32x4 sc[4];
            #pragma unroll
            for (int nt = 0; nt < 4; nt++) {
                short8 k0f = *(const short8*)&kb[qoff + (j0 + nt * 16 + n16) * 64 + quad * 8];
                short8 k1f = *(const short8*)&kb[qoff + (j0 + nt * 16 + n16) * 64 + 32 + quad * 8];
                f32x4 s = {};
                s = MFMA16(aq0, k0f, s);
                s = MFMA16(aq1, k1f, s);
                sc[nt] = s;
            }
            float zl[4][4];
            #pragma unroll
            for (int nt = 0; nt < 4; nt++) {
                int jloc = nt * 16 + n16;
                #pragma unroll
                for (int r = 0; r < 4; r++) {
                    float zz = scale * (sc[nt][r] + biasv);
                    if (diag && jloc > iloc + r) zz = -1e30f;
                    zl[nt][r] = zz;
                }
            }
            float cm[4];
            #pragma unroll
            for (int r = 0; r < 4; r++)
                cm[r] = fmaxf(fmaxf(zl[0][r], zl[1][r]), fmaxf(zl[2][r], zl[3][r]));
            #pragma unroll
            for (int off = 1; off < 16; off <<= 1)
                #pragma unroll
                for (int r = 0; r < 4; r++)
                    cm[r] = fmaxf(cm[r], __shfl_xor(cm[r], off));
            float mnew[4], alpha[4], rsum[4], pr[4][4];
            #pragma unroll
            for (int r = 0; r < 4; r++) {
                mnew[r] = fmaxf(mrow[r], cm[r]);
                alpha[r] = __expf(mrow[r] - mnew[r]);
            }
            #pragma unroll
            for (int nt = 0; nt < 4; nt++)
                #pragma unroll
                for (int r = 0; r < 4; r++)
                    pr[nt][r] = __expf(zl[nt][r] - mnew[r]);
            #pragma unroll
            for (int r = 0; r < 4; r++)
                rsum[r] = (pr[0][r] + pr[1][r]) + (pr[2][r] + pr[3][r]);
            #pragma unroll
            for (int off = 1; off < 16; off <<= 1)
                #pragma unroll
                for (int r = 0; r < 4; r++)
                    rsum[r] += __shfl_xor(rsum[r], off);
            #pragma unroll
            for (int r = 0; r < 4; r++) {
                lrow[r] = lrow[r] * alpha[r] + rsum[r];
                mrow[r] = mnew[r];
            }
            #pragma unroll
            for (int et = 0; et < 4; et++)
                #pragma unroll
                for (int r = 0; r < 4; r++)
                    oacc[et][r] *= alpha[r];
            #pragma unroll
            for (int nt = 0; nt < 4; nt++) {
                int s = nt >> 1, c = (nt & 1) * 16 + n16;
                #pragma unroll
                for (int r = 0; r < 4; r++)
                    Pw[s * 640 + (quad * 4 + r) * 40 + c] = f2bf(pr[nt][r]);
            }
            short8 pa0 = *(const short8*)&Pw[0 * 640 + n16 * 40 + quad * 8];
            short8 pa1 = *(const short8*)&Pw[1 * 640 + n16 * 40 + quad * 8];
            #pragma unroll
            for (int et = 0; et < 4; et++) {
                const int vrow = (bh * 64 + et * 16 + n16) * 2048;
                short8 v0 = *(const short8*)&vT[vrow + j0 + quad * 8];
                short8 v1 = *(const short8*)&vT[vrow + j0 + 32 + quad * 8];
                oacc[et] = MFMA16(pa0, v0, oacc[et]);
                oacc[et] = MFMA16(pa1, v1, oacc[et]);
            }
        }
        const int pb = (bh * 8 + split) * 64;
        #pragma unroll
        for (int et = 0; et < 4; et++)
            #pragma unroll
            for (int r = 0; r < 4; r++)
                Opart[(pb + w * 16 + quad * 4 + r) * 64 + et * 16 + n16] = oacc[et][r];
        if (n16 == 0) {
            #pragma unroll
            for (int r = 0; r < 4; r++) {
                Mp[pb + w * 16 + quad * 4 + r] = mrow[r];
                Lp[pb + w * 16 + quad * 4 + r] = lrow[r];
            }
        }
    }
}

// ---------------------------------------------------------------------------
// Kernel 4: merge 8 partials per (b,h). grid 16 blocks, 256 threads.
// ---------------------------------------------------------------------------
__global__ __launch_bounds__(256) void attn31_merge(
    const float* __restrict__ Opart, const float* __restrict__ Mp,
    const float* __restrict__ Lp, unsigned short* __restrict__ voutb)
{
    const int bh = blockIdx.x, b = bh >> 3, h = bh & 7;
    const int t = threadIdx.x;
    const int row = t >> 2, c0 = (t & 3) * 16;
    float ms[8];
    float M = -1e30f;
    #pragma unroll
    for (int s = 0; s < 8; s++) {
        ms[s] = Mp[(bh * 8 + s) * 64 + row];
        M = fmaxf(M, ms[s]);
    }
    float L = 0.f;
    float es[8];
    #pragma unroll
    for (int s = 0; s < 8; s++) {
        es[s] = __expf(ms[s] - M);
        L += Lp[(bh * 8 + s) * 64 + row] * es[s];
    }
    float acc[16] = {};
    #pragma unroll
    for (int s = 0; s < 8; s++) {
        const float* op = &Opart[((bh * 8 + s) * 64 + row) * 64 + c0];
        #pragma unroll
        for (int k = 0; k < 4; k++) {
            float4 v = *(const float4*)&op[k * 4];
            acc[k*4+0] += v.x * es[s]; acc[k*4+1] += v.y * es[s];
            acc[k*4+2] += v.z * es[s]; acc[k*4+3] += v.w * es[s];
        }
    }
    const float inv = 1.f / L;
    const int l = 31 * 64 + row;
    u16x4 pk;
    #pragma unroll
    for (int k = 0; k < 4; k++) {
        pk[0] = f2bf(acc[k*4+0] * inv); pk[1] = f2bf(acc[k*4+1] * inv);
        pk[2] = f2bf(acc[k*4+2] * inv); pk[3] = f2bf(acc[k*4+3] * inv);
        *(u16x4*)&voutb[(b * 2048 + l) * 512 + h * 64 + c0 + k * 4] = pk;
    }
}

// ---------------------------------------------------------------------------
// Kernel 5: out = voutb(4096x512) @ Wo^T + bo -> fp32, gld-swizzled staging
// ---------------------------------------------------------------------------
__global__ __launch_bounds__(256) void gemm_out(
    const unsigned short* __restrict__ ab, const unsigned short* __restrict__ wo,
    const float* __restrict__ bo, float* __restrict__ out)
{
    const int n0 = blockIdx.x * 128, m0 = blockIdx.y * 128;
    __shared__ unsigned short Al[128 * 32];
    __shared__ unsigned short Bl[128 * 32];
    const int t = threadIdx.x;
    const int lane = t & 63, w = t >> 6;
    const int wm = (w >> 1) * 64, wn = (w & 1) * 64;
    const int quad = lane >> 4, n16 = lane & 15;
    const int rA = lane >> 2;
    const int cG = (((lane & 3) ^ ((rA >> 1) & 3))) * 8;
    const int slotq = (quad ^ ((n16 >> 1) & 3)) * 8;
    const int fragA = (wm >> 4) * 512 + n16 * 32 + slotq;
    const int fragB = (wn >> 4) * 512 + n16 * 32 + slotq;
    f32x4 acc[4][4] = {};
    for (int k0 = 0; k0 < 512; k0 += 32) {
        __syncthreads();
        #pragma unroll
        for (int i = 0; i < 2; i++) {
            const int row = w * 32 + i * 16;
            GLD16(&ab[(m0 + row + rA) * 512 + k0 + cG], &Al[row * 32]);
            GLD16(&wo[(n0 + row + rA) * 512 + k0 + cG], &Bl[row * 32]);
        }
        __syncthreads();
        short8 af[4], bfr[4];
        #pragma unroll
        for (int i = 0; i < 4; i++) af[i]  = *(const short8*)&Al[fragA + i * 512];
        #pragma unroll
        for (int i = 0; i < 4; i++) bfr[i] = *(const short8*)&Bl[fragB + i * 512];
        #pragma unroll
        for (int mi = 0; mi < 4; mi++)
            #pragma unroll
            for (int ni = 0; ni < 4; ni++)
                acc[mi][ni] = MFMA16(af[mi], bfr[ni], acc[mi][ni]);
    }
    #pragma unroll
    for (int mi = 0; mi < 4; mi++) {
        #pragma unroll
        for (int ni = 0; ni < 4; ni++) {
            const int n = n0 + wn + ni * 16 + n16;
            const int mb = m0 + wm + mi * 16 + quad * 4;
            const float bias = bo[n];
            f32x4 v = acc[mi][ni];
            #pragma unroll
            for (int r = 0; r < 4; r++)
                out[(mb + r) * 512 + n] = v[r] + bias;
        }
    }
}

// ---------------------------------------------------------------------------
extern "C" void kernel_launch(void* const* d_in, const int* in_sizes, int n_in,
                              void* d_out, int out_size, void* d_ws, size_t ws_size,
                              hipStream_t stream)
{
    const float* x        = (const float*)d_in[0];
    const float* Wq       = (const float*)d_in[1];
    const float* bq       = (const float*)d_in[2];
    const float* Wk       = (const float*)d_in[3];
    const float* bk       = (const float*)d_in[4];
    const float* Wv       = (const float*)d_in[5];
    const float* bv       = (const float*)d_in[6];
    const float* Wo       = (const float*)d_in[7];
    const float* bo       = (const float*)d_in[8];
    const float* bias_emb = (const float*)d_in[9];

    unsigned short* xb  = (unsigned short*)d_ws;      // 2097152 elems (4 MB)
    unsigned short* wb  = xb + 2097152;               // 4 * 262144
    unsigned short* qb  = wb + 1048576;               // (B,H,L,E)
    unsigned short* kb  = qb + 2097152;               // (B,H,L,E)
    unsigned short* vT  = kb + 2097152;               // (B,H,E,L)
    unsigned short* vob = vT + 2097152;               // (B,L,H*E)

    // attn31 scratch reuses xb (dead after gemm_qkv)
    float* Opart = (float*)xb;
    float* Mp    = Opart + 524288;
    float* Lp    = Mp + 8192;

    hipLaunchKernelGGL(convertk, dim3(3072), dim3(256), 0, stream,
                       x, Wq, Wk, Wv, Wo, xb, wb);
    hipLaunchKernelGGL(gemm_qkv, dim3(4, 32, 3), dim3(256), 0, stream,
                       xb, wb, bq, bk, bv, qb, kb, vT);
    hipLaunchKernelGGL(attn_all, dim3(39, 8, 2), dim3(256), 0, stream,
                       qb, kb, vT, bias_emb, vob, Opart, Mp, Lp);
    hipLaunchKernelGGL(attn31_merge, dim3(16), dim3(256), 0, stream,
                       Opart, Mp, Lp, vob);
    hipLaunchKernelGGL(gemm_out, dim3(4, 32, 1), dim3(256), 0, stream,
                       vob, wb + 3 * 262144, bo, (float*)d_out);
}

// Round 5
// 128.053 us; speedup vs baseline: 1.9322x; 1.0315x over previous
//
#include <hip/hip_runtime.h>

typedef __attribute__((ext_vector_type(8))) short short8;
typedef __attribute__((ext_vector_type(4))) float f32x4;
typedef __attribute__((ext_vector_type(4))) unsigned short u16x4;

#define MFMA16(a, b, c) __builtin_amdgcn_mfma_f32_16x16x32_bf16(a, b, c, 0, 0, 0)

// global_load_lds: per-lane 16B from global -> wave-uniform LDS base + lane*16
#define GLD16(gp, lp) __builtin_amdgcn_global_load_lds( \
    (const __attribute__((address_space(1))) unsigned int*)(gp), \
    (__attribute__((address_space(3))) unsigned int*)(lp), 16, 0, 0)

__device__ __forceinline__ unsigned short f2bf(float f) {
    union { float f; unsigned int u; } v; v.f = f;
    unsigned int r = (v.u + 0x7fffu + ((v.u >> 16) & 1u)) >> 16;
    return (unsigned short)r;
}

// ---------------------------------------------------------------------------
// Kernel 1: fp32 -> bf16 convert: x (2097152) then Wq,Wk,Wv,Wo (262144 each)
// ---------------------------------------------------------------------------
__global__ __launch_bounds__(256) void convertk(
    const float* __restrict__ x, const float* __restrict__ wq,
    const float* __restrict__ wk, const float* __restrict__ wv,
    const float* __restrict__ wo, unsigned short* __restrict__ xb,
    unsigned short* __restrict__ wb)
{
    int i = (blockIdx.x * 256 + threadIdx.x) * 4;
    const float* src;
    unsigned short* dst;
    if (i < 2097152) { src = x + i; dst = xb + i; }
    else {
        int j = i - 2097152;
        int w = j >> 18;
        int o = j & 262143;
        src = (w == 0 ? wq : w == 1 ? wk : w == 2 ? wv : wo) + o;
        dst = wb + j;
    }
    float4 v = *(const float4*)src;
    u16x4 p;
    p[0] = f2bf(v.x); p[1] = f2bf(v.y); p[2] = f2bf(v.z); p[3] = f2bf(v.w);
    *(u16x4*)dst = p;
}

// ---------------------------------------------------------------------------
// Kernel 2: QKV GEMM, 64x128 tiles (768 blocks = 3/CU), fused RoPE epilogue.
// Staging via swizzled global_load_lds (16-row x 32-col groups):
//   stage: lane fetches global col-block (lane&3)^((row>>1)&3)
//   read : lane (n16,quad) reads slot quad^((n16>>1)&3)  -> 8 words/bank (opt)
// Waves 2x2 over (64m,128n): wave tile 32x64, acc 2x4.
// ---------------------------------------------------------------------------
__global__ __launch_bounds__(256) void gemm_qkv(
    const unsigned short* __restrict__ xb, const unsigned short* __restrict__ wb,
    const float* __restrict__ bq, const float* __restrict__ bk,
    const float* __restrict__ bv,
    unsigned short* __restrict__ qb, unsigned short* __restrict__ kb,
    unsigned short* __restrict__ vT)
{
    const int z = blockIdx.z;
    const unsigned short* Wz = wb + z * 262144;
    const int n0 = blockIdx.x * 128, m0 = blockIdx.y * 64;
    __shared__ unsigned short Al[64 * 32];    // 4 KB
    __shared__ unsigned short Bl[128 * 32];   // 8 KB
    const int t = threadIdx.x;
    const int lane = t & 63, w = t >> 6;
    const int wrow = (w >> 1) * 32, wcol = (w & 1) * 64;
    const int quad = lane >> 4, n16 = lane & 15;
    const int rA = lane >> 2;
    const int cG = (((lane & 3) ^ ((rA >> 1) & 3))) * 8;
    const int slotq = (quad ^ ((n16 >> 1) & 3)) * 8;
    const int fragA0 = (wrow >> 4) * 512 + n16 * 32 + slotq;
    const int fragB0 = (wcol >> 4) * 512 + n16 * 32 + slotq;
    f32x4 acc[2][4] = {};
    for (int k0 = 0; k0 < 512; k0 += 32) {
        __syncthreads();
        GLD16(&xb[(m0 + w * 16 + rA) * 512 + k0 + cG],      &Al[(w * 16) * 32]);
        GLD16(&Wz[(n0 + w * 32 + rA) * 512 + k0 + cG],      &Bl[(w * 32) * 32]);
        GLD16(&Wz[(n0 + w * 32 + 16 + rA) * 512 + k0 + cG], &Bl[(w * 32 + 16) * 32]);
        __syncthreads();
        short8 af[2], bfr[4];
        #pragma unroll
        for (int i = 0; i < 2; i++) af[i]  = *(const short8*)&Al[fragA0 + i * 512];
        #pragma unroll
        for (int i = 0; i < 4; i++) bfr[i] = *(const short8*)&Bl[fragB0 + i * 512];
        #pragma unroll
        for (int mi = 0; mi < 2; mi++)
            #pragma unroll
            for (int ni = 0; ni < 4; ni++)
                acc[mi][ni] = MFMA16(af[mi], bfr[ni], acc[mi][ni]);
    }
    const float* bias_p = (z == 0) ? bq : (z == 1) ? bk : bv;
    unsigned short* dst01 = (z == 0) ? qb : kb;
    #pragma unroll
    for (int mi = 0; mi < 2; mi++) {
        #pragma unroll
        for (int ni = 0; ni < 4; ni++) {
            const int n = n0 + wcol + ni * 16 + n16;
            const int mb = m0 + wrow + mi * 16 + quad * 4;
            const float bias = bias_p[n];
            const int h = n >> 6;
            const int e_lo = ni * 16 + n16;        // = n & 63 (wcol ≡ 0 mod 64)
            f32x4 v = acc[mi][ni];
            if (z < 2) {
                float vr[4];
                #pragma unroll
                for (int r = 0; r < 4; r++) vr[r] = v[r] + bias;
                if (ni < 2) {   // e < 32: RoPE (compile-time uniform)
                    const int j = e_lo >> 1;
                    const float theta = exp2f(-(float)j * 0.8304820237218405f);
                    #pragma unroll
                    for (int r = 0; r < 4; r++) {
                        int l = (mb + r) & 2047;
                        float s, c;
                        __sincosf((float)l * theta, &s, &c);
                        float p = __shfl_xor(vr[r], 1);
                        vr[r] = (e_lo & 1) ? (c * vr[r] + s * p) : (c * vr[r] - s * p);
                    }
                }
                #pragma unroll
                for (int r = 0; r < 4; r++) {
                    int m = mb + r, b = m >> 11, l = m & 2047;
                    dst01[((b * 8 + h) * 2048 + l) * 64 + e_lo] = f2bf(vr[r]);
                }
            } else {
                int b = mb >> 11, l = mb & 2047;
                u16x4 pk;
                #pragma unroll
                for (int r = 0; r < 4; r++) pk[r] = f2bf(v[r] + bias);
                *(u16x4*)&vT[((b * 8 + h) * 64 + e_lo) * 2048 + l] = pk;
            }
        }
    }
}

// ---------------------------------------------------------------------------
// Kernel 3: combined attention. grid (39, 8, 2).
//   blockIdx.x < 31 : diagonal var = x (one-pass softmax, single chunk)
//   blockIdx.x >= 31: var-31 split s = x-31, 4 chunks, emits partials.
// ---------------------------------------------------------------------------
__global__ __launch_bounds__(256) void attn_all(
    const unsigned short* __restrict__ qb, const unsigned short* __restrict__ kb,
    const unsigned short* __restrict__ vT, const float* __restrict__ bias_emb,
    unsigned short* __restrict__ voutb,
    float* __restrict__ Opart, float* __restrict__ Mp, float* __restrict__ Lp)
{
    const int xid = blockIdx.x, h = blockIdx.y, b = blockIdx.z;
    const int t = threadIdx.x, lane = t & 63, w = t >> 6;
    const int quad = lane >> 4, n16 = lane & 15;
    const int bh = b * 8 + h;
    __shared__ unsigned short Pl[4 * 1280];
    unsigned short* Pw = &Pl[w * 1280];
    const int qoff = bh * 2048 * 64;
    const float scale = 0.125f;
    const float bias_same = bias_emb[8 + h];
    const int iloc = w * 16 + quad * 4;

    if (xid < 31) {
        const int var = xid;
        const int m0 = var * 64 + w * 16;
        const int j0 = var * 64;
        short8 aq0 = *(const short8*)&qb[qoff + (m0 + n16) * 64 + quad * 8];
        short8 aq1 = *(const short8*)&qb[qoff + (m0 + n16) * 64 + 32 + quad * 8];
        f32x4 sc[4];
        #pragma unroll
        for (int nt = 0; nt < 4; nt++) {
            short8 k0f = *(const short8*)&kb[qoff + (j0 + nt * 16 + n16) * 64 + quad * 8];
            short8 k1f = *(const short8*)&kb[qoff + (j0 + nt * 16 + n16) * 64 + 32 + quad * 8];
            f32x4 s = {};
            s = MFMA16(aq0, k0f, s);
            s = MFMA16(aq1, k1f, s);
            sc[nt] = s;
        }
        float zl[4][4];
        #pragma unroll
        for (int nt = 0; nt < 4; nt++) {
            int jloc = nt * 16 + n16;
            #pragma unroll
            for (int r = 0; r < 4; r++) {
                float zz = scale * (sc[nt][r] + bias_same);
                if (jloc > iloc + r) zz = -1e30f;
                zl[nt][r] = zz;
            }
        }
        float cm[4], rsum[4], pr[4][4];
        #pragma unroll
        for (int r = 0; r < 4; r++)
            cm[r] = fmaxf(fmaxf(zl[0][r], zl[1][r]), fmaxf(zl[2][r], zl[3][r]));
        #pragma unroll
        for (int off = 1; off < 16; off <<= 1)
            #pragma unroll
            for (int r = 0; r < 4; r++)
                cm[r] = fmaxf(cm[r], __shfl_xor(cm[r], off));
        #pragma unroll
        for (int nt = 0; nt < 4; nt++)
            #pragma unroll
            for (int r = 0; r < 4; r++)
                pr[nt][r] = __expf(zl[nt][r] - cm[r]);
        #pragma unroll
        for (int r = 0; r < 4; r++)
            rsum[r] = (pr[0][r] + pr[1][r]) + (pr[2][r] + pr[3][r]);
        #pragma unroll
        for (int off = 1; off < 16; off <<= 1)
            #pragma unroll
            for (int r = 0; r < 4; r++)
                rsum[r] += __shfl_xor(rsum[r], off);
        #pragma unroll
        for (int nt = 0; nt < 4; nt++) {
            int s = nt >> 1, c = (nt & 1) * 16 + n16;
            #pragma unroll
            for (int r = 0; r < 4; r++)
                Pw[s * 640 + (quad * 4 + r) * 40 + c] = f2bf(pr[nt][r]);
        }
        short8 pa0 = *(const short8*)&Pw[0 * 640 + n16 * 40 + quad * 8];
        short8 pa1 = *(const short8*)&Pw[1 * 640 + n16 * 40 + quad * 8];
        f32x4 oacc[4] = {};
        #pragma unroll
        for (int et = 0; et < 4; et++) {
            const int vrow = (bh * 64 + et * 16 + n16) * 2048;
            short8 v0 = *(const short8*)&vT[vrow + j0 + quad * 8];
            short8 v1 = *(const short8*)&vT[vrow + j0 + 32 + quad * 8];
            oacc[et] = MFMA16(pa0, v0, oacc[et]);
            oacc[et] = MFMA16(pa1, v1, oacc[et]);
        }
        #pragma unroll
        for (int et = 0; et < 4; et++) {
            #pragma unroll
            for (int r = 0; r < 4; r++) {
                float o = oacc[et][r] / rsum[r];
                int l = m0 + quad * 4 + r;
                voutb[(b * 2048 + l) * 512 + h * 64 + et * 16 + n16] = f2bf(o);
            }
        }
    } else {
        const int split = xid - 31;
        const int m0 = 31 * 64 + w * 16;
        const float bias_diff = bias_emb[h];
        short8 aq0 = *(const short8*)&qb[qoff + (m0 + n16) * 64 + quad * 8];
        short8 aq1 = *(const short8*)&qb[qoff + (m0 + n16) * 64 + 32 + quad * 8];
        f32x4 oacc[4] = {};
        float mrow[4], lrow[4];
        #pragma unroll
        for (int r = 0; r < 4; r++) { mrow[r] = -1e30f; lrow[r] = 0.f; }
        #pragma unroll
        for (int ci = 0; ci < 4; ci++) {
            const int chunk = split * 4 + ci;
            const bool diag = (chunk == 31);
            const float biasv = diag ? bias_same : bias_diff;
            const int j0 = chunk * 64;
            f32x4 sc[4];
            #pragma unroll
            for (int nt = 0; nt < 4; nt++) {
                short8 k0f = *(const short8*)&kb[qoff + (j0 + nt * 16 + n16) * 64 + quad * 8];
                short8 k1f = *(const short8*)&kb[qoff + (j0 + nt * 16 + n16) * 64 + 32 + quad * 8];
                f32x4 s = {};
                s = MFMA16(aq0, k0f, s);
                s = MFMA16(aq1, k1f, s);
                sc[nt] = s;
            }
            float zl[4][4];
            #pragma unroll
            for (int nt = 0; nt < 4; nt++) {
                int jloc = nt * 16 + n16;
                #pragma unroll
                for (int r = 0; r < 4; r++) {
                    float zz = scale * (sc[nt][r] + biasv);
                    if (diag && jloc > iloc + r) zz = -1e30f;
                    zl[nt][r] = zz;
                }
            }
            float cm[4];
            #pragma unroll
            for (int r = 0; r < 4; r++)
                cm[r] = fmaxf(fmaxf(zl[0][r], zl[1][r]), fmaxf(zl[2][r], zl[3][r]));
            #pragma unroll
            for (int off = 1; off < 16; off <<= 1)
                #pragma unroll
                for (int r = 0; r < 4; r++)
                    cm[r] = fmaxf(cm[r], __shfl_xor(cm[r], off));
            float mnew[4], alpha[4], rsum[4], pr[4][4];
            #pragma unroll
            for (int r = 0; r < 4; r++) {
                mnew[r] = fmaxf(mrow[r], cm[r]);
                alpha[r] = __expf(mrow[r] - mnew[r]);
            }
            #pragma unroll
            for (int nt = 0; nt < 4; nt++)
                #pragma unroll
                for (int r = 0; r < 4; r++)
                    pr[nt][r] = __expf(zl[nt][r] - mnew[r]);
            #pragma unroll
            for (int r = 0; r < 4; r++)
                rsum[r] = (pr[0][r] + pr[1][r]) + (pr[2][r] + pr[3][r]);
            #pragma unroll
            for (int off = 1; off < 16; off <<= 1)
                #pragma unroll
                for (int r = 0; r < 4; r++)
                    rsum[r] += __shfl_xor(rsum[r], off);
            #pragma unroll
            for (int r = 0; r < 4; r++) {
                lrow[r] = lrow[r] * alpha[r] + rsum[r];
                mrow[r] = mnew[r];
            }
            #pragma unroll
            for (int et = 0; et < 4; et++)
                #pragma unroll
                for (int r = 0; r < 4; r++)
                    oacc[et][r] *= alpha[r];
            #pragma unroll
            for (int nt = 0; nt < 4; nt++) {
                int s = nt >> 1, c = (nt & 1) * 16 + n16;
                #pragma unroll
                for (int r = 0; r < 4; r++)
                    Pw[s * 640 + (quad * 4 + r) * 40 + c] = f2bf(pr[nt][r]);
            }
            short8 pa0 = *(const short8*)&Pw[0 * 640 + n16 * 40 + quad * 8];
            short8 pa1 = *(const short8*)&Pw[1 * 640 + n16 * 40 + quad * 8];
            #pragma unroll
            for (int et = 0; et < 4; et++) {
                const int vrow = (bh * 64 + et * 16 + n16) * 2048;
                short8 v0 = *(const short8*)&vT[vrow + j0 + quad * 8];
                short8 v1 = *(const short8*)&vT[vrow + j0 + 32 + quad * 8];
                oacc[et] = MFMA16(pa0, v0, oacc[et]);
                oacc[et] = MFMA16(pa1, v1, oacc[et]);
            }
        }
        const int pb = (bh * 8 + split) * 64;
        #pragma unroll
        for (int et = 0; et < 4; et++)
            #pragma unroll
            for (int r = 0; r < 4; r++)
                Opart[(pb + w * 16 + quad * 4 + r) * 64 + et * 16 + n16] = oacc[et][r];
        if (n16 == 0) {
            #pragma unroll
            for (int r = 0; r < 4; r++) {
                Mp[pb + w * 16 + quad * 4 + r] = mrow[r];
                Lp[pb + w * 16 + quad * 4 + r] = lrow[r];
            }
        }
    }
}

// ---------------------------------------------------------------------------
// Kernel 4: merge 8 partials per (b,h). grid 16 blocks, 256 threads.
// ---------------------------------------------------------------------------
__global__ __launch_bounds__(256) void attn31_merge(
    const float* __restrict__ Opart, const float* __restrict__ Mp,
    const float* __restrict__ Lp, unsigned short* __restrict__ voutb)
{
    const int bh = blockIdx.x, b = bh >> 3, h = bh & 7;
    const int t = threadIdx.x;
    const int row = t >> 2, c0 = (t & 3) * 16;
    float ms[8];
    float M = -1e30f;
    #pragma unroll
    for (int s = 0; s < 8; s++) {
        ms[s] = Mp[(bh * 8 + s) * 64 + row];
        M = fmaxf(M, ms[s]);
    }
    float L = 0.f;
    float es[8];
    #pragma unroll
    for (int s = 0; s < 8; s++) {
        es[s] = __expf(ms[s] - M);
        L += Lp[(bh * 8 + s) * 64 + row] * es[s];
    }
    float acc[16] = {};
    #pragma unroll
    for (int s = 0; s < 8; s++) {
        const float* op = &Opart[((bh * 8 + s) * 64 + row) * 64 + c0];
        #pragma unroll
        for (int k = 0; k < 4; k++) {
            float4 v = *(const float4*)&op[k * 4];
            acc[k*4+0] += v.x * es[s]; acc[k*4+1] += v.y * es[s];
            acc[k*4+2] += v.z * es[s]; acc[k*4+3] += v.w * es[s];
        }
    }
    const float inv = 1.f / L;
    const int l = 31 * 64 + row;
    u16x4 pk;
    #pragma unroll
    for (int k = 0; k < 4; k++) {
        pk[0] = f2bf(acc[k*4+0] * inv); pk[1] = f2bf(acc[k*4+1] * inv);
        pk[2] = f2bf(acc[k*4+2] * inv); pk[3] = f2bf(acc[k*4+3] * inv);
        *(u16x4*)&voutb[(b * 2048 + l) * 512 + h * 64 + c0 + k * 4] = pk;
    }
}

// ---------------------------------------------------------------------------
// Kernel 5: out = voutb(4096x512) @ Wo^T + bo -> fp32.  64x64 tiles,
// 512 blocks = 2/CU.  Waves 2x2 over (64m,64n): wave tile 32x32, acc 2x2.
// ---------------------------------------------------------------------------
__global__ __launch_bounds__(256) void gemm_out(
    const unsigned short* __restrict__ ab, const unsigned short* __restrict__ wo,
    const float* __restrict__ bo, float* __restrict__ out)
{
    const int n0 = blockIdx.x * 64, m0 = blockIdx.y * 64;
    __shared__ unsigned short Al[64 * 32];
    __shared__ unsigned short Bl[64 * 32];
    const int t = threadIdx.x;
    const int lane = t & 63, w = t >> 6;
    const int wrow = (w >> 1) * 32, wcol = (w & 1) * 32;
    const int quad = lane >> 4, n16 = lane & 15;
    const int rA = lane >> 2;
    const int cG = (((lane & 3) ^ ((rA >> 1) & 3))) * 8;
    const int slotq = (quad ^ ((n16 >> 1) & 3)) * 8;
    const int fragA0 = (wrow >> 4) * 512 + n16 * 32 + slotq;
    const int fragB0 = (wcol >> 4) * 512 + n16 * 32 + slotq;
    f32x4 acc[2][2] = {};
    for (int k0 = 0; k0 < 512; k0 += 32) {
        __syncthreads();
        GLD16(&ab[(m0 + w * 16 + rA) * 512 + k0 + cG], &Al[(w * 16) * 32]);
        GLD16(&wo[(n0 + w * 16 + rA) * 512 + k0 + cG], &Bl[(w * 16) * 32]);
        __syncthreads();
        short8 af[2], bfr[2];
        #pragma unroll
        for (int i = 0; i < 2; i++) af[i]  = *(const short8*)&Al[fragA0 + i * 512];
        #pragma unroll
        for (int i = 0; i < 2; i++) bfr[i] = *(const short8*)&Bl[fragB0 + i * 512];
        #pragma unroll
        for (int mi = 0; mi < 2; mi++)
            #pragma unroll
            for (int ni = 0; ni < 2; ni++)
                acc[mi][ni] = MFMA16(af[mi], bfr[ni], acc[mi][ni]);
    }
    #pragma unroll
    for (int mi = 0; mi < 2; mi++) {
        #pragma unroll
        for (int ni = 0; ni < 2; ni++) {
            const int n = n0 + wcol + ni * 16 + n16;
            const int mb = m0 + wrow + mi * 16 + quad * 4;
            const float bias = bo[n];
            f32x4 v = acc[mi][ni];
            #pragma unroll
            for (int r = 0; r < 4; r++)
                out[(mb + r) * 512 + n] = v[r] + bias;
        }
    }
}

// ---------------------------------------------------------------------------
extern "C" void kernel_launch(void* const* d_in, const int* in_sizes, int n_in,
                              void* d_out, int out_size, void* d_ws, size_t ws_size,
                              hipStream_t stream)
{
    const float* x        = (const float*)d_in[0];
    const float* Wq       = (const float*)d_in[1];
    const float* bq       = (const float*)d_in[2];
    const float* Wk       = (const float*)d_in[3];
    const float* bk       = (const float*)d_in[4];
    const float* Wv       = (const float*)d_in[5];
    const float* bv       = (const float*)d_in[6];
    const float* Wo       = (const float*)d_in[7];
    const float* bo       = (const float*)d_in[8];
    const float* bias_emb = (const float*)d_in[9];

    unsigned short* xb  = (unsigned short*)d_ws;      // 2097152 elems (4 MB)
    unsigned short* wb  = xb + 2097152;               // 4 * 262144
    unsigned short* qb  = wb + 1048576;               // (B,H,L,E)
    unsigned short* kb  = qb + 2097152;               // (B,H,L,E)
    unsigned short* vT  = kb + 2097152;               // (B,H,E,L)
    unsigned short* vob = vT + 2097152;               // (B,L,H*E)

    // attn31 scratch reuses xb (dead after gemm_qkv)
    float* Opart = (float*)xb;
    float* Mp    = Opart + 524288;
    float* Lp    = Mp + 8192;

    hipLaunchKernelGGL(convertk, dim3(3072), dim3(256), 0, stream,
                       x, Wq, Wk, Wv, Wo, xb, wb);
    hipLaunchKernelGGL(gemm_qkv, dim3(4, 64, 3), dim3(256), 0, stream,
                       xb, wb, bq, bk, bv, qb, kb, vT);
    hipLaunchKernelGGL(attn_all, dim3(39, 8, 2), dim3(256), 0, stream,
                       qb, kb, vT, bias_emb, vob, Opart, Mp, Lp);
    hipLaunchKernelGGL(attn31_merge, dim3(16), dim3(256), 0, stream,
                       Opart, Mp, Lp, vob);
    hipLaunchKernelGGL(gemm_out, dim3(8, 64), dim3(256), 0, stream,
                       vob, wb + 3 * 262144, bo, (float*)d_out);
}